// Round 9
// baseline (151.152 us; speedup 1.0000x reference)
//
#include <hip/hip_runtime.h>
#include <hip/hip_bf16.h>

// RelativeAttention: out = softmax_j(mask((query@Wq)·(key@Wk)^T)) @ (key@Wv) @ Wu + bu
// B=4, T=1024, E=1024, H=8, D=128. All GEMMs via bf16 MFMA (f32 accum).

typedef __attribute__((ext_vector_type(8))) short bf16x8;   // 8 bf16 (4 VGPRs)
typedef __attribute__((ext_vector_type(4))) float f32x4;    // MFMA C/D frag

static constexpr int BB = 4;
static constexpr int TT = 1024;
static constexpr int EE = 1024;
static constexpr int HH = 8;
static constexpr int DD = 128;

// ---------- helpers ----------
static __device__ __forceinline__ unsigned short f2b(float x) {
  union { float f; unsigned int u; } c; c.f = x;
  unsigned int r = c.u + 0x7fffu + ((c.u >> 16) & 1u);   // RTN-even
  return (unsigned short)(r >> 16);
}

static __device__ __forceinline__ unsigned int cvtpk(float lo, float hi) {
  unsigned int r;
  asm("v_cvt_pk_bf16_f32 %0, %1, %2" : "=v"(r) : "v"(lo), "v"(hi));
  return r;   // low16 = bf16(lo), high16 = bf16(hi)
}

static __device__ __forceinline__ float exp2x(float x) {   // 2^x, 1 instr
  float r;
  asm("v_exp_f32 %0, %1" : "=v"(r) : "v"(x));
  return r;
}

static __device__ __forceinline__ void gload_lds16(const void* g, void* l) {
  __builtin_amdgcn_global_load_lds(
      (const __attribute__((address_space(1))) unsigned int*)g,
      (__attribute__((address_space(3))) unsigned int*)l, 16, 0, 0);
}

// ---------- f32 -> bf16 convert for query & key ----------
__global__ __launch_bounds__(256) void cvt_kernel(
    const float* __restrict__ qf, const float* __restrict__ kf,
    unsigned short* __restrict__ qb, unsigned short* __restrict__ kb) {
  int i = blockIdx.x * 256 + threadIdx.x;   // each thread: 4 elements of each
  float4 a = ((const float4*)qf)[i];
  ushort4 oa; oa.x = f2b(a.x); oa.y = f2b(a.y); oa.z = f2b(a.z); oa.w = f2b(a.w);
  ((ushort4*)qb)[i] = oa;
  float4 b = ((const float4*)kf)[i];
  ushort4 ob; ob.x = f2b(b.x); ob.y = f2b(b.y); ob.z = f2b(b.z); ob.w = f2b(b.w);
  ((ushort4*)kb)[i] = ob;
}

// ---------- weight transpose-convert: W (K x N) f32 -> Wt (N x K) bf16 ----------
// scale folds log2(e) into Wq so softmax can run in exp2 domain.
struct WT4 { const float* src[4]; unsigned short* dst[4]; float scale[4]; };

__global__ __launch_bounds__(256) void wtrans_kernel(WT4 wt) {
  const float* src = wt.src[blockIdx.z];
  unsigned short* dst = wt.dst[blockIdx.z];
  const float sc = wt.scale[blockIdx.z];
  __shared__ float tile[32][33];
  int n0 = blockIdx.x * 32, k0 = blockIdx.y * 32;
  int tx = threadIdx.x, ty = threadIdx.y;   // (32, 8)
#pragma unroll
  for (int i = 0; i < 4; ++i)
    tile[ty + i * 8][tx] = src[(size_t)(k0 + ty + i * 8) * EE + n0 + tx];
  __syncthreads();
#pragma unroll
  for (int i = 0; i < 4; ++i)
    dst[(size_t)(n0 + ty + i * 8) * EE + k0 + tx] = f2b(tile[tx][ty + i * 8] * sc);
}

// ---------- V transpose: vp [b,kt, h*128+d] -> vt [b,h,d, kt] (bf16) ----------
__global__ __launch_bounds__(256) void vtrans_kernel(
    const unsigned short* __restrict__ vp, unsigned short* __restrict__ vt) {
  int bh = blockIdx.z; int b = bh >> 3, h = bh & 7;
  int d0 = blockIdx.x * 32, kt0 = blockIdx.y * 32;
  __shared__ unsigned short tile[32][33];
  int tx = threadIdx.x, ty = threadIdx.y;
#pragma unroll
  for (int i = 0; i < 4; ++i)
    tile[ty + i * 8][tx] =
        vp[(size_t)(b * TT + kt0 + ty + i * 8) * EE + h * DD + d0 + tx];
  __syncthreads();
#pragma unroll
  for (int i = 0; i < 4; ++i)
    vt[(size_t)((b * HH + h) * DD + d0 + ty + i * 8) * TT + kt0 + tx] =
        tile[tx][ty + i * 8];
}

// ---------- mask -> bitmask: mbits[row][t] bit j = (mask[row][t*64+j] != 0) ----
__global__ __launch_bounds__(256) void maskpack_kernel(
    const int* __restrict__ mask, unsigned long long* __restrict__ mbits) {
  int row = blockIdx.x * 4 + (threadIdx.x >> 6);   // row < B*TT = 4096
  int lane = threadIdx.x & 63;
  const int* mrow = mask + (size_t)row * TT;
  unsigned long long myw = 0;
#pragma unroll
  for (int jw = 0; jw < 16; ++jw) {
    unsigned long long bal = __ballot(mrow[jw * 64 + lane] != 0);
    if (lane == jw) myw = bal;
  }
  if (lane < 16) mbits[(size_t)row * 16 + lane] = myw;
}

// ---------- GEMM core (bf16 out): C[M,N] = A[M,K] @ Bt[N,K]^T ----------
// 128x128 tile, BK=64 (half the barriers of BK=32), 4 waves (2x2).
// LDS rows are 128B -> naive reads would be 16-way bank conflicts; fixed
// with the T2 XOR chunk swizzle applied BOTH sides: global source chunk
// pre-swizzled (c ^= row&7), reads XOR the same term (involution, g21).
static __device__ __forceinline__ void gemm_core(
    const unsigned short* __restrict__ A, const unsigned short* __restrict__ Bt,
    unsigned short* __restrict__ Cb) {
  constexpr int K = EE, N = EE;
  __shared__ __align__(16) unsigned short As[128 * 64];
  __shared__ __align__(16) unsigned short Bs[128 * 64];
  const int tid = threadIdx.x, lane = tid & 63, w = tid >> 6;
  const int wm = w >> 1, wn = w & 1;
  const int bm = blockIdx.x, bn = blockIdx.y;
  const int g4 = lane >> 4, l15 = lane & 15;

  f32x4 acc[4][4] = {};

  for (int kt = 0; kt < K / 64; ++kt) {
    const int k0 = kt * 64;
#pragma unroll
    for (int it = 0; it < 4; ++it) {
      int idx = it * 256 + tid;           // 16B chunk id: 128 rows x 8 chunks
      int r = idx >> 3, c = (idx & 7) ^ (r & 7);
      gload_lds16(A + (size_t)(bm * 128 + r) * K + k0 + c * 8, As + idx * 8);
      gload_lds16(Bt + (size_t)(bn * 128 + r) * K + k0 + c * 8, Bs + idx * 8);
    }
    __syncthreads();
    bf16x8 af[2][4], bf[2][4];
#pragma unroll
    for (int kc2 = 0; kc2 < 2; ++kc2) {
      int co = ((kc2 * 4 + g4) ^ (l15 & 7)) * 8;   // swizzled chunk offset
#pragma unroll
      for (int i = 0; i < 4; ++i) {
        af[kc2][i] = *(const bf16x8*)(As + (wm * 64 + i * 16 + l15) * 64 + co);
        bf[kc2][i] = *(const bf16x8*)(Bs + (wn * 64 + i * 16 + l15) * 64 + co);
      }
    }
#pragma unroll
    for (int kc2 = 0; kc2 < 2; ++kc2)
#pragma unroll
      for (int i = 0; i < 4; ++i)
#pragma unroll
        for (int j = 0; j < 4; ++j)
          acc[i][j] = __builtin_amdgcn_mfma_f32_16x16x32_bf16(
              af[kc2][i], bf[kc2][j], acc[i][j], 0, 0, 0);
    __syncthreads();
  }

  // epilogue: C/D layout col=lane&15, row=(lane>>4)*4+reg
  const int rr = g4 * 4;
#pragma unroll
  for (int i = 0; i < 4; ++i)
#pragma unroll
    for (int j = 0; j < 4; ++j) {
      int row = bm * 128 + wm * 64 + i * 16 + rr;
      int col = bn * 128 + wn * 64 + j * 16 + l15;
#pragma unroll
      for (int r = 0; r < 4; ++r)
        Cb[(size_t)(row + r) * N + col] = f2b(acc[i][j][r]);
    }
}

struct Gemm3 { const unsigned short* A[3]; const unsigned short* Bt[3];
               unsigned short* C[3]; };

__global__ __launch_bounds__(256) void proj_gemm_kernel(Gemm3 g) {
  int z = blockIdx.z;
  gemm_core(g.A[z], g.Bt[z], g.C[z]);
}

// ---------- output GEMM: 64x128 tile (512 blocks -> 2 blocks/CU) ----------
__global__ __launch_bounds__(256) void out_gemm_kernel(
    const unsigned short* __restrict__ A, const unsigned short* __restrict__ Bt,
    float* __restrict__ Cf, const float* __restrict__ bias) {
  constexpr int K = EE, N = EE;
  __shared__ __align__(16) unsigned short As[64 * 32];
  __shared__ __align__(16) unsigned short Bs[128 * 32];
  const int tid = threadIdx.x, lane = tid & 63, w = tid >> 6;
  const int wm = w >> 1, wn = w & 1;
  const int bm = blockIdx.x, bn = blockIdx.y;
  const int g4 = lane >> 4, l15 = lane & 15;

  f32x4 acc[2][4] = {};

  for (int kt = 0; kt < K / 32; ++kt) {
    const int k0 = kt * 32;
    {
      int row = tid >> 2, c = tid & 3;               // A: 256 x 16B chunks
      gload_lds16(A + (size_t)(bm * 64 + row) * K + k0 + c * 8, As + tid * 8);
    }
#pragma unroll
    for (int it = 0; it < 2; ++it) {                 // B: 512 x 16B chunks
      int idx = it * 256 + tid;
      int row = idx >> 2, c = idx & 3;
      gload_lds16(Bt + (size_t)(bn * 128 + row) * K + k0 + c * 8, Bs + idx * 8);
    }
    __syncthreads();
    bf16x8 af[2], bf[4];
#pragma unroll
    for (int i = 0; i < 2; ++i)
      af[i] = *(const bf16x8*)(As + (wm * 32 + i * 16 + l15) * 32 + g4 * 8);
#pragma unroll
    for (int j = 0; j < 4; ++j)
      bf[j] = *(const bf16x8*)(Bs + (wn * 64 + j * 16 + l15) * 32 + g4 * 8);
#pragma unroll
    for (int i = 0; i < 2; ++i)
#pragma unroll
      for (int j = 0; j < 4; ++j)
        acc[i][j] = __builtin_amdgcn_mfma_f32_16x16x32_bf16(af[i], bf[j],
                                                            acc[i][j], 0, 0, 0);
    __syncthreads();
  }

  const int rr = g4 * 4;
#pragma unroll
  for (int i = 0; i < 2; ++i)
#pragma unroll
    for (int j = 0; j < 4; ++j) {
      int row = bm * 64 + wm * 32 + i * 16 + rr;
      int col = bn * 128 + wn * 64 + j * 16 + l15;
#pragma unroll
      for (int r = 0; r < 4; ++r)
        Cf[(size_t)(row + r) * N + col] = acc[i][j][r] + bias[col];
    }
}

// ---------- fused attention ----------
// 4 waves x 16 q-rows, KVBLK=64, swapped QK^T (lane owns q-row = l15),
// exp2-domain softmax, defer-max THR=8, bitmask, XCD-aware remap.
// K double-buffered in LDS (32KB) via async global_load_lds; V read
// DIRECTLY from global (vt) into register fragments at tile top — K/V
// panels are XCD-L2-resident (R8: FETCH=compulsory), so staging V in LDS
// was pure overhead (m169 lesson). V loads issue before K(t+1) prefetch
// so PV's wait is a counted vmcnt, not a drain.
__global__ __launch_bounds__(256, 2) void attn_kernel(
    const unsigned short* __restrict__ q, const unsigned short* __restrict__ k,
    const unsigned short* __restrict__ vt,
    const unsigned long long* __restrict__ mbits,
    unsigned short* __restrict__ av) {
  extern __shared__ __align__(16) char smem[];   // 2 x 16KB K dbuf

  const int tid = threadIdx.x, lane = tid & 63, w = tid >> 6;
  // ---- XCD-aware bijective remap (512 blocks = 8 XCD x 64) ----
  const int orig = blockIdx.x + 16 * blockIdx.y + 128 * blockIdx.z;
  const int qt = (orig >> 3) & 15;
  const int pair = ((orig & 7) << 2) | (orig >> 7);   // [0,32)
  const int h = pair & 7, b = pair >> 3;
  const int i0 = qt * 64 + w * 16;
  const int g4 = lane >> 4, l15 = lane & 15;
  const int swz = (l15 & 7) << 4;

  // Q fragments (operand layout: elem row=lane&15, k=(lane>>4)*8+j)
  bf16x8 aq[4];
  {
    const unsigned short* qb =
        q + (size_t)(b * TT + i0 + l15) * EE + h * DD + g4 * 8;
#pragma unroll
    for (int kc = 0; kc < 4; ++kc) aq[kc] = *(const bf16x8*)(qb + kc * 32);
  }

  // K staging source pointers (pre-swizzled chunk: c ^= row&7, g21)
  const unsigned short* kb0 = k + (size_t)(b * TT) * EE + h * DD;
  const unsigned short* kptr[4];
  int chunkb[4];
#pragma unroll
  for (int p = 0; p < 4; ++p) {
    int base = p * 256 + w * 64;           // wave-uniform 16B-chunk base
    int idx = base + lane;
    int kr = idx >> 4, kcc = (idx & 15) ^ (kr & 7);
    kptr[p] = kb0 + (size_t)kr * EE + kcc * 8;
    chunkb[p] = base * 16;                 // byte offset in LDS
  }

  // V fragment base: B-frag row d = dt*16 + l15, kt-slice = h2*32 + g4*8
  const unsigned short* vfb =
      vt + (size_t)((b * HH + h) * DD + l15) * TT + g4 * 8;

  // mask bit words: word t covers kt in [t*64, t*64+64), bit = kt&63
  const unsigned long long* mb = mbits + ((size_t)(b * TT + i0 + l15) << 4);
  unsigned long long mcur = mb[0];

  // K LDS read bases: addr = kb_[kc] + nt*4096 (row stride 256B)
  int kb_[4];
#pragma unroll
  for (int kc = 0; kc < 4; ++kc)
    kb_[kc] = l15 * 256 + ((kc * 64 + g4 * 16) ^ swz);

  // prologue: stage K(0) into buf 0
#pragma unroll
  for (int p = 0; p < 4; ++p) gload_lds16(kptr[p], smem + chunkb[p]);
#pragma unroll
  for (int p = 0; p < 4; ++p) kptr[p] += 64 * EE;

  f32x4 oacc[8] = {};
  float mrun = -__builtin_inff(), lrun = 0.f;   // per lane: q-row = l15

  __syncthreads();
  int bufoff = 0;   // byte offset of current K buffer (0 / 16384)

  for (int t = 0; t < 16; ++t) {
    // ---- V(t) fragments: direct global -> VGPR (issued FIRST so the
    //      PV wait leaves the K(t+1) prefetch in flight) ----
    bf16x8 vr[2][8];
    {
      const unsigned short* vtt = vfb + t * 64;
#pragma unroll
      for (int h2 = 0; h2 < 2; ++h2)
#pragma unroll
        for (int dt = 0; dt < 8; ++dt)
          vr[h2][dt] =
              *(const bf16x8*)(vtt + (size_t)dt * 16 * TT + h2 * 32);
    }

    // ---- next tile: mask word + async K prefetch into other buffer ----
    unsigned long long mnext = 0;
    if (t < 15) {
      mnext = mb[t + 1];
      int dst = bufoff ^ 16384;
#pragma unroll
      for (int p = 0; p < 4; ++p)
        gload_lds16(kptr[p], smem + dst + chunkb[p]);
#pragma unroll
      for (int p = 0; p < 4; ++p) kptr[p] += 64 * EE;
    }

    // ---- S^T = K Q^T: lane holds q-row l15, kt = nt*16 + g4*4 + r ----
    f32x4 sacc[4] = {};
    __builtin_amdgcn_s_setprio(1);
#pragma unroll
    for (int kc = 0; kc < 4; ++kc)
#pragma unroll
      for (int nt = 0; nt < 4; ++nt) {
        bf16x8 bk = *(const bf16x8*)(smem + kb_[kc] + nt * 4096);
        sacc[nt] = __builtin_amdgcn_mfma_f32_16x16x32_bf16(bk, aq[kc],
                                                           sacc[nt], 0, 0, 0);
      }
    __builtin_amdgcn_s_setprio(0);

    // ---- mask: bit==0 -> -1e9 (exp2 of it underflows to 0) ----
    {
      unsigned int wlo = (unsigned int)mcur, whi = (unsigned int)(mcur >> 32);
#pragma unroll
      for (int nt = 0; nt < 4; ++nt) {
        unsigned int ww = (nt < 2) ? wlo : whi;
        int bb = (nt & 1) * 16 + g4 * 4;
#pragma unroll
        for (int r = 0; r < 4; ++r)
          if (((ww >> (bb + r)) & 1u) == 0u) sacc[nt][r] = -1e9f;
      }
    }

    // ---- row max: lane-local 16 + 2 shfl ----
    float mx = sacc[0][0];
#pragma unroll
    for (int nt = 0; nt < 4; ++nt)
#pragma unroll
      for (int r = 0; r < 4; ++r) mx = fmaxf(mx, sacc[nt][r]);
    mx = fmaxf(mx, __shfl_xor(mx, 16, 64));
    mx = fmaxf(mx, __shfl_xor(mx, 32, 64));

    // ---- defer-max (THR=8 in log2 domain -> P bounded by 256) ----
    if (__any(mx > mrun + 8.f)) {
      float mnew = fmaxf(mrun, mx);
      float sc = exp2x(mrun - mnew);   // exp2(-inf)=0 on first tile
      lrun *= sc;
      mrun = mnew;
      float scO[4];
#pragma unroll
      for (int r = 0; r < 4; ++r)
        scO[r] = __shfl(sc, (lane & 48) | (((lane & 48) >> 2) + r), 64);
#pragma unroll
      for (int dt = 0; dt < 8; ++dt)
#pragma unroll
        for (int r = 0; r < 4; ++r) oacc[dt][r] *= scO[r];
    }

    // ---- exp2 + row sum (lane-local + 2 shfl) ----
    float p[4][4];
    float s0 = 0.f;
#pragma unroll
    for (int nt = 0; nt < 4; ++nt)
#pragma unroll
      for (int r = 0; r < 4; ++r) {
        float pv = exp2x(sacc[nt][r] - mrun);
        p[nt][r] = pv;
        s0 += pv;
      }
    s0 += __shfl_xor(s0, 16, 64);
    s0 += __shfl_xor(s0, 32, 64);
    lrun += s0;

    // ---- P -> PV A-frags in-register (cvt_pk + 12 shfl) ----
    unsigned int paw[2][4];
#pragma unroll
    for (int h2 = 0; h2 < 2; ++h2) {
      unsigned int D0a = cvtpk(p[2 * h2][0], p[2 * h2][1]);
      unsigned int D1a = cvtpk(p[2 * h2][2], p[2 * h2][3]);
      unsigned int D0b = cvtpk(p[2 * h2 + 1][0], p[2 * h2 + 1][1]);
      unsigned int D1b = cvtpk(p[2 * h2 + 1][2], p[2 * h2 + 1][3]);
      unsigned int r1 = __shfl_xor(g4 < 2 ? D0a : D0b, 16, 64);
      unsigned int r2 = __shfl_xor(g4 < 2 ? D1a : D1b, 16, 64);
      unsigned int r3 = __shfl_xor(g4 == 0 ? D0b : D0a, 32, 64);
      unsigned int r4 = __shfl_xor(g4 == 0 ? D1b : D1a, 32, 64);
      unsigned int r5 = __shfl_xor(g4 == 2 ? D0a : D0b, 48, 64);
      unsigned int r6 = __shfl_xor(g4 == 2 ? D1a : D1b, 48, 64);
      paw[h2][0] = g4 == 0 ? D0a : g4 == 1 ? r5 : g4 == 2 ? r3 : r1;
      paw[h2][1] = g4 == 0 ? D1a : g4 == 1 ? r6 : g4 == 2 ? r4 : r2;
      paw[h2][2] = g4 == 0 ? r1 : g4 == 1 ? r3 : g4 == 2 ? r5 : D0b;
      paw[h2][3] = g4 == 0 ? r2 : g4 == 1 ? r4 : g4 == 2 ? r6 : D1b;
    }

    // ---- PV: O += P (16x64) @ V (64x128), V from registers ----
    __builtin_amdgcn_s_setprio(1);
#pragma unroll
    for (int h2 = 0; h2 < 2; ++h2) {
      union { unsigned int u[4]; bf16x8 v; } pau;
      pau.u[0] = paw[h2][0]; pau.u[1] = paw[h2][1];
      pau.u[2] = paw[h2][2]; pau.u[3] = paw[h2][3];
#pragma unroll
      for (int dt = 0; dt < 8; ++dt)
        oacc[dt] = __builtin_amdgcn_mfma_f32_16x16x32_bf16(
            pau.v, vr[h2][dt], oacc[dt], 0, 0, 0);
    }
    __builtin_amdgcn_s_setprio(0);

    // ---- one barrier: drains K prefetch + orders K buffer reuse ----
    __syncthreads();
    bufoff ^= 16384;
#pragma unroll
    for (int kc = 0; kc < 4; ++kc) kb_[kc] ^= 16384;
    mcur = mnext;
  }

  // ---- epilogue: att_vec = O / l (l at lane l15=qrow; O rows at g4*4+r) ----
  float linv[4];
#pragma unroll
  for (int r = 0; r < 4; ++r)
    linv[r] = 1.f / __shfl(lrun, (lane & 48) | (((lane & 48) >> 2) + r), 64);
  unsigned short* ob =
      av + (size_t)(b * TT + i0 + g4 * 4) * EE + h * DD + l15;
#pragma unroll
  for (int dt = 0; dt < 8; ++dt)
#pragma unroll
    for (int r = 0; r < 4; ++r)
      ob[(size_t)r * EE + dt * 16] = f2b(oacc[dt][r] * linv[r]);
}

// ---------- launch ----------
extern "C" void kernel_launch(void* const* d_in, const int* in_sizes, int n_in,
                              void* d_out, int out_size, void* d_ws,
                              size_t ws_size, hipStream_t stream) {
  const float* query = (const float*)d_in[0];
  const float* key   = (const float*)d_in[1];
  const int*   mask  = (const int*)d_in[2];
  const float* Wq    = (const float*)d_in[3];
  const float* Wk    = (const float*)d_in[4];
  const float* Wv    = (const float*)d_in[5];
  const float* Wu    = (const float*)d_in[6];
  const float* bu    = (const float*)d_in[7];
  float* out = (float*)d_out;

  char* ws = (char*)d_ws;
  const size_t MB = 1024 * 1024;
  unsigned short* qbf = (unsigned short*)(ws);             // 8MB bf16 query
  unsigned short* kbf = (unsigned short*)(ws + 8 * MB);    // 8MB bf16 key
  unsigned short* Wqt = (unsigned short*)(ws + 16 * MB);   // 2MB each, N x K
  unsigned short* Wkt = (unsigned short*)(ws + 18 * MB);
  unsigned short* Wvt = (unsigned short*)(ws + 20 * MB);
  unsigned short* Wut = (unsigned short*)(ws + 22 * MB);
  unsigned short* qp  = (unsigned short*)(ws + 24 * MB);   // q proj
  unsigned short* kp  = (unsigned short*)(ws + 32 * MB);   // k proj
  unsigned short* vp  = (unsigned short*)(ws + 40 * MB);   // v proj (dead after vtrans)
  unsigned short* vtb = (unsigned short*)(ws + 48 * MB);   // v transposed
  unsigned short* av  = (unsigned short*)(ws + 56 * MB);   // attention out
  unsigned long long* mbt = (unsigned long long*)(ws + 40 * MB);  // 512KB, reuses vp

  cvt_kernel<<<4096, 256, 0, stream>>>(query, key, qbf, kbf);

  WT4 wt; wt.src[0] = Wq; wt.src[1] = Wk; wt.src[2] = Wv; wt.src[3] = Wu;
  wt.dst[0] = Wqt; wt.dst[1] = Wkt; wt.dst[2] = Wvt; wt.dst[3] = Wut;
  wt.scale[0] = 1.4426950408889634f;   // log2(e): softmax in exp2 domain
  wt.scale[1] = 1.0f; wt.scale[2] = 1.0f; wt.scale[3] = 1.0f;
  wtrans_kernel<<<dim3(32, 32, 4), dim3(32, 8), 0, stream>>>(wt);

  Gemm3 g3;
  g3.A[0] = qbf; g3.A[1] = kbf; g3.A[2] = kbf;
  g3.Bt[0] = Wqt; g3.Bt[1] = Wkt; g3.Bt[2] = Wvt;
  g3.C[0] = qp; g3.C[1] = kp; g3.C[2] = vp;
  proj_gemm_kernel<<<dim3(32, 8, 3), 256, 0, stream>>>(g3);

  vtrans_kernel<<<dim3(4, 32, 32), dim3(32, 8), 0, stream>>>(vp, vtb);

  // after vtrans, vp region is dead -> pack mask bits there
  maskpack_kernel<<<1024, 256, 0, stream>>>(mask, mbt);

  attn_kernel<<<dim3(16, 8, 4), 256, 32768, stream>>>(qp, kp, vtb, mbt, av);

  out_gemm_kernel<<<dim3(64, 8), 256, 0, stream>>>(av, Wut, out, bu);
}

// Round 10
// 118.029 us; speedup vs baseline: 1.2806x; 1.2806x over previous
//
#include <hip/hip_runtime.h>
#include <hip/hip_bf16.h>

// RelativeAttention: out = softmax_j(mask((query@Wq)·(key@Wk)^T)) @ (key@Wv) @ Wu + bu
// B=4, T=1024, E=1024, H=8, D=128. All GEMMs via bf16 MFMA (f32 accum).

typedef __attribute__((ext_vector_type(8))) short bf16x8;   // 8 bf16 (4 VGPRs)
typedef __attribute__((ext_vector_type(4))) float f32x4;    // MFMA C/D frag

static constexpr int BB = 4;
static constexpr int TT = 1024;
static constexpr int EE = 1024;
static constexpr int HH = 8;
static constexpr int DD = 128;

// ---------- helpers ----------
static __device__ __forceinline__ unsigned short f2b(float x) {
  union { float f; unsigned int u; } c; c.f = x;
  unsigned int r = c.u + 0x7fffu + ((c.u >> 16) & 1u);   // RTN-even
  return (unsigned short)(r >> 16);
}

static __device__ __forceinline__ unsigned int cvtpk(float lo, float hi) {
  unsigned int r;
  asm("v_cvt_pk_bf16_f32 %0, %1, %2" : "=v"(r) : "v"(lo), "v"(hi));
  return r;   // low16 = bf16(lo), high16 = bf16(hi)
}

static __device__ __forceinline__ float exp2x(float x) {   // 2^x, 1 instr
  float r;
  asm("v_exp_f32 %0, %1" : "=v"(r) : "v"(x));
  return r;
}

static __device__ __forceinline__ void gload_lds16(const void* g, void* l) {
  __builtin_amdgcn_global_load_lds(
      (const __attribute__((address_space(1))) unsigned int*)g,
      (__attribute__((address_space(3))) unsigned int*)l, 16, 0, 0);
}

// ---------- f32 -> bf16 convert for query & key ----------
__global__ __launch_bounds__(256) void cvt_kernel(
    const float* __restrict__ qf, const float* __restrict__ kf,
    unsigned short* __restrict__ qb, unsigned short* __restrict__ kb) {
  int i = blockIdx.x * 256 + threadIdx.x;   // each thread: 4 elements of each
  float4 a = ((const float4*)qf)[i];
  ushort4 oa; oa.x = f2b(a.x); oa.y = f2b(a.y); oa.z = f2b(a.z); oa.w = f2b(a.w);
  ((ushort4*)qb)[i] = oa;
  float4 b = ((const float4*)kf)[i];
  ushort4 ob; ob.x = f2b(b.x); ob.y = f2b(b.y); ob.z = f2b(b.z); ob.w = f2b(b.w);
  ((ushort4*)kb)[i] = ob;
}

// ---------- weight transpose-convert: W (K x N) f32 -> Wt (N x K) bf16 ----------
// scale folds log2(e) into Wq so softmax can run in exp2 domain.
struct WT4 { const float* src[4]; unsigned short* dst[4]; float scale[4]; };

__global__ __launch_bounds__(256) void wtrans_kernel(WT4 wt) {
  const float* src = wt.src[blockIdx.z];
  unsigned short* dst = wt.dst[blockIdx.z];
  const float sc = wt.scale[blockIdx.z];
  __shared__ float tile[32][33];
  int n0 = blockIdx.x * 32, k0 = blockIdx.y * 32;
  int tx = threadIdx.x, ty = threadIdx.y;   // (32, 8)
#pragma unroll
  for (int i = 0; i < 4; ++i)
    tile[ty + i * 8][tx] = src[(size_t)(k0 + ty + i * 8) * EE + n0 + tx];
  __syncthreads();
#pragma unroll
  for (int i = 0; i < 4; ++i)
    dst[(size_t)(n0 + ty + i * 8) * EE + k0 + tx] = f2b(tile[tx][ty + i * 8] * sc);
}

// ---------- V transpose: vp [b,kt, h*128+d] -> vt [b,h,d, kt] (bf16) ----------
__global__ __launch_bounds__(256) void vtrans_kernel(
    const unsigned short* __restrict__ vp, unsigned short* __restrict__ vt) {
  int bh = blockIdx.z; int b = bh >> 3, h = bh & 7;
  int d0 = blockIdx.x * 32, kt0 = blockIdx.y * 32;
  __shared__ unsigned short tile[32][33];
  int tx = threadIdx.x, ty = threadIdx.y;
#pragma unroll
  for (int i = 0; i < 4; ++i)
    tile[ty + i * 8][tx] =
        vp[(size_t)(b * TT + kt0 + ty + i * 8) * EE + h * DD + d0 + tx];
  __syncthreads();
#pragma unroll
  for (int i = 0; i < 4; ++i)
    vt[(size_t)((b * HH + h) * DD + d0 + ty + i * 8) * TT + kt0 + tx] =
        tile[tx][ty + i * 8];
}

// ---------- mask -> bitmask: mbits[row][t] bit j = (mask[row][t*64+j] != 0) ----
__global__ __launch_bounds__(256) void maskpack_kernel(
    const int* __restrict__ mask, unsigned long long* __restrict__ mbits) {
  int row = blockIdx.x * 4 + (threadIdx.x >> 6);   // row < B*TT = 4096
  int lane = threadIdx.x & 63;
  const int* mrow = mask + (size_t)row * TT;
  unsigned long long myw = 0;
#pragma unroll
  for (int jw = 0; jw < 16; ++jw) {
    unsigned long long bal = __ballot(mrow[jw * 64 + lane] != 0);
    if (lane == jw) myw = bal;
  }
  if (lane < 16) mbits[(size_t)row * 16 + lane] = myw;
}

// ---------- GEMM core (bf16 out): C[M,N] = A[M,K] @ Bt[N,K]^T ----------
// 128x128 tile, BK=64 (half the barriers of BK=32), 4 waves (2x2).
// T2 XOR chunk swizzle applied BOTH sides (g21): global source chunk
// pre-swizzled (c ^= row&7), reads XOR the same term (involution).
static __device__ __forceinline__ void gemm_core(
    const unsigned short* __restrict__ A, const unsigned short* __restrict__ Bt,
    unsigned short* __restrict__ Cb) {
  constexpr int K = EE, N = EE;
  __shared__ __align__(16) unsigned short As[128 * 64];
  __shared__ __align__(16) unsigned short Bs[128 * 64];
  const int tid = threadIdx.x, lane = tid & 63, w = tid >> 6;
  const int wm = w >> 1, wn = w & 1;
  const int bm = blockIdx.x, bn = blockIdx.y;
  const int g4 = lane >> 4, l15 = lane & 15;

  f32x4 acc[4][4] = {};

  for (int kt = 0; kt < K / 64; ++kt) {
    const int k0 = kt * 64;
#pragma unroll
    for (int it = 0; it < 4; ++it) {
      int idx = it * 256 + tid;           // 16B chunk id: 128 rows x 8 chunks
      int r = idx >> 3, c = (idx & 7) ^ (r & 7);
      gload_lds16(A + (size_t)(bm * 128 + r) * K + k0 + c * 8, As + idx * 8);
      gload_lds16(Bt + (size_t)(bn * 128 + r) * K + k0 + c * 8, Bs + idx * 8);
    }
    __syncthreads();
    bf16x8 af[2][4], bf[2][4];
#pragma unroll
    for (int kc2 = 0; kc2 < 2; ++kc2) {
      int co = ((kc2 * 4 + g4) ^ (l15 & 7)) * 8;   // swizzled chunk offset
#pragma unroll
      for (int i = 0; i < 4; ++i) {
        af[kc2][i] = *(const bf16x8*)(As + (wm * 64 + i * 16 + l15) * 64 + co);
        bf[kc2][i] = *(const bf16x8*)(Bs + (wn * 64 + i * 16 + l15) * 64 + co);
      }
    }
#pragma unroll
    for (int kc2 = 0; kc2 < 2; ++kc2)
#pragma unroll
      for (int i = 0; i < 4; ++i)
#pragma unroll
        for (int j = 0; j < 4; ++j)
          acc[i][j] = __builtin_amdgcn_mfma_f32_16x16x32_bf16(
              af[kc2][i], bf[kc2][j], acc[i][j], 0, 0, 0);
    __syncthreads();
  }

  // epilogue: C/D layout col=lane&15, row=(lane>>4)*4+reg
  const int rr = g4 * 4;
#pragma unroll
  for (int i = 0; i < 4; ++i)
#pragma unroll
    for (int j = 0; j < 4; ++j) {
      int row = bm * 128 + wm * 64 + i * 16 + rr;
      int col = bn * 128 + wn * 64 + j * 16 + l15;
#pragma unroll
      for (int r = 0; r < 4; ++r)
        Cb[(size_t)(row + r) * N + col] = f2b(acc[i][j][r]);
    }
}

struct Gemm3 { const unsigned short* A[3]; const unsigned short* Bt[3];
               unsigned short* C[3]; };

__global__ __launch_bounds__(256) void proj_gemm_kernel(Gemm3 g) {
  int z = blockIdx.z;
  gemm_core(g.A[z], g.Bt[z], g.C[z]);
}

// ---------- output GEMM: 64x128 tile (512 blocks -> 2 blocks/CU) ----------
__global__ __launch_bounds__(256) void out_gemm_kernel(
    const unsigned short* __restrict__ A, const unsigned short* __restrict__ Bt,
    float* __restrict__ Cf, const float* __restrict__ bias) {
  constexpr int K = EE, N = EE;
  __shared__ __align__(16) unsigned short As[64 * 32];
  __shared__ __align__(16) unsigned short Bs[128 * 32];
  const int tid = threadIdx.x, lane = tid & 63, w = tid >> 6;
  const int wm = w >> 1, wn = w & 1;
  const int bm = blockIdx.x, bn = blockIdx.y;
  const int g4 = lane >> 4, l15 = lane & 15;

  f32x4 acc[2][4] = {};

  for (int kt = 0; kt < K / 32; ++kt) {
    const int k0 = kt * 32;
    {
      int row = tid >> 2, c = tid & 3;               // A: 256 x 16B chunks
      gload_lds16(A + (size_t)(bm * 64 + row) * K + k0 + c * 8, As + tid * 8);
    }
#pragma unroll
    for (int it = 0; it < 2; ++it) {                 // B: 512 x 16B chunks
      int idx = it * 256 + tid;
      int row = idx >> 2, c = idx & 3;
      gload_lds16(Bt + (size_t)(bn * 128 + row) * K + k0 + c * 8, Bs + idx * 8);
    }
    __syncthreads();
    bf16x8 af[2], bf[4];
#pragma unroll
    for (int i = 0; i < 2; ++i)
      af[i] = *(const bf16x8*)(As + (wm * 32 + i * 16 + l15) * 32 + g4 * 8);
#pragma unroll
    for (int j = 0; j < 4; ++j)
      bf[j] = *(const bf16x8*)(Bs + (wn * 64 + j * 16 + l15) * 32 + g4 * 8);
#pragma unroll
    for (int i = 0; i < 2; ++i)
#pragma unroll
      for (int j = 0; j < 4; ++j)
        acc[i][j] = __builtin_amdgcn_mfma_f32_16x16x32_bf16(af[i], bf[j],
                                                            acc[i][j], 0, 0, 0);
    __syncthreads();
  }

  const int rr = g4 * 4;
#pragma unroll
  for (int i = 0; i < 2; ++i)
#pragma unroll
    for (int j = 0; j < 4; ++j) {
      int row = bm * 64 + wm * 32 + i * 16 + rr;
      int col = bn * 128 + wn * 64 + j * 16 + l15;
#pragma unroll
      for (int r = 0; r < 4; ++r)
        Cf[(size_t)(row + r) * N + col] = acc[i][j][r] + bias[col];
    }
}

// ---------- fused attention ----------
// R8 structure (K+V dbuf in LDS via async global_load_lds, swapped QK^T,
// exp2 softmax, defer-max, bitmask, XCD remap) + T3/T4 counted-vmcnt
// pipeline: raw s_barrier at tile top (no drain), prefetch issued after
// the barrier, s_waitcnt vmcnt(8) leaves the new tile's 8 loads in
// flight across the whole compute phase. Race-safety: writes at iter t
// target buf[(t+1)&1], last read at iter t-1, and all waves passed the
// top barrier after iter t-1 => no overlap. sched_barrier(0) after the
// counted wait stops ds_reads hoisting above it (guide rule #18 — the
// compiler can't see the gload_lds->LDS dependency).
__global__ __launch_bounds__(256) void attn_kernel(
    const unsigned short* __restrict__ q, const unsigned short* __restrict__ k,
    const unsigned short* __restrict__ vt,
    const unsigned long long* __restrict__ mbits,
    unsigned short* __restrict__ av) {
  extern __shared__ __align__(16) char smem[];   // [0,32K) K dbuf; [32K,64K) V dbuf

  const int tid = threadIdx.x, lane = tid & 63, w = tid >> 6;
  // ---- XCD-aware bijective remap (512 blocks = 8 XCD x 64) ----
  const int orig = blockIdx.x + 16 * blockIdx.y + 128 * blockIdx.z;
  const int qt = (orig >> 3) & 15;
  const int pair = ((orig & 7) << 2) | (orig >> 7);   // [0,32)
  const int h = pair & 7, b = pair >> 3;
  const int i0 = qt * 64 + w * 16;
  const int g4 = lane >> 4, l15 = lane & 15;
  const int swz = (l15 & 7) << 4;

  // Q fragments (operand layout: elem row=lane&15, k=(lane>>4)*8+j)
  bf16x8 aq[4];
  {
    const unsigned short* qb =
        q + (size_t)(b * TT + i0 + l15) * EE + h * DD + g4 * 8;
#pragma unroll
    for (int kc = 0; kc < 4; ++kc) aq[kc] = *(const bf16x8*)(qb + kc * 32);
  }

  // staging source pointers (pre-swizzled chunk: c ^= row&7, g21)
  const unsigned short* kb0 = k + (size_t)(b * TT) * EE + h * DD;
  const unsigned short* vb0 = vt + (size_t)((b * HH + h) * DD) * TT;
  const unsigned short* kptr[4];
  const unsigned short* vptr[4];
  int chunkb[4];
#pragma unroll
  for (int p = 0; p < 4; ++p) {
    int base = p * 256 + w * 64;           // wave-uniform 16B-chunk base
    int idx = base + lane;
    int kr = idx >> 4, kcc = (idx & 15) ^ (kr & 7);
    kptr[p] = kb0 + (size_t)kr * EE + kcc * 8;
    int vr = idx >> 3, vcc = (idx & 7) ^ (vr & 7);
    vptr[p] = vb0 + (size_t)vr * TT + vcc * 8;
    chunkb[p] = base * 16;                 // byte offset in LDS
  }

  // mask bit words: word t covers kt in [t*64, t*64+64), bit = kt&63
  const unsigned long long* mb = mbits + ((size_t)(b * TT + i0 + l15) << 4);
  unsigned long long mcur = mb[0];

  // LDS read bases (byte): addr = kb_[kc] + nt*4096 ; vb_[h2] + dt*2048.
  int kb_[4], vb_[2];
#pragma unroll
  for (int kc = 0; kc < 4; ++kc)
    kb_[kc] = l15 * 256 + ((kc * 64 + g4 * 16) ^ swz);
#pragma unroll
  for (int h2 = 0; h2 < 2; ++h2)
    vb_[h2] = 32768 + l15 * 128 + ((h2 * 64 + g4 * 16) ^ swz);

  // prologue: stage tile 0 into buf 0, full drain once
#pragma unroll
  for (int p = 0; p < 4; ++p) {
    gload_lds16(kptr[p], smem + chunkb[p]);
    gload_lds16(vptr[p], smem + 32768 + chunkb[p]);
  }
#pragma unroll
  for (int p = 0; p < 4; ++p) { kptr[p] += 64 * EE; vptr[p] += 64; }

  f32x4 oacc[8] = {};
  float mrun = -__builtin_inff(), lrun = 0.f;   // per lane: q-row = l15

  __syncthreads();
  int bufoff = 0;   // byte offset of current K buffer (0 / 16384)

  for (int t = 0; t < 16; ++t) {
    // ---- top barrier (raw, no vmcnt drain): all waves done with t-1 ----
    if (t > 0) __builtin_amdgcn_s_barrier();

    // ---- issue next tile (mask first, then 8 async stages), then wait
    //      for THIS tile's data only: vmcnt(8) keeps the 8 new loads in
    //      flight across the whole compute phase ----
    unsigned long long mnext = 0;
    if (t < 15) {
      mnext = mb[t + 1];
      int dst = bufoff ^ 16384;
#pragma unroll
      for (int p = 0; p < 4; ++p) {
        gload_lds16(kptr[p], smem + dst + chunkb[p]);
        gload_lds16(vptr[p], smem + 32768 + dst + chunkb[p]);
      }
#pragma unroll
      for (int p = 0; p < 4; ++p) { kptr[p] += 64 * EE; vptr[p] += 64; }
      asm volatile("s_waitcnt vmcnt(8)" ::: "memory");
      __builtin_amdgcn_sched_barrier(0);
    } else {
      asm volatile("s_waitcnt vmcnt(0)" ::: "memory");
      __builtin_amdgcn_sched_barrier(0);
    }

    // ---- S^T = K Q^T: lane holds q-row l15, kt = nt*16 + g4*4 + r ----
    f32x4 sacc[4] = {};
    __builtin_amdgcn_s_setprio(1);
#pragma unroll
    for (int kc = 0; kc < 4; ++kc)
#pragma unroll
      for (int nt = 0; nt < 4; ++nt) {
        bf16x8 bk = *(const bf16x8*)(smem + kb_[kc] + nt * 4096);
        sacc[nt] = __builtin_amdgcn_mfma_f32_16x16x32_bf16(bk, aq[kc],
                                                           sacc[nt], 0, 0, 0);
      }
    __builtin_amdgcn_s_setprio(0);

    // ---- mask: bit==0 -> -1e9 (exp2 of it underflows to 0) ----
    {
      unsigned int wlo = (unsigned int)mcur, whi = (unsigned int)(mcur >> 32);
#pragma unroll
      for (int nt = 0; nt < 4; ++nt) {
        unsigned int ww = (nt < 2) ? wlo : whi;
        int bb = (nt & 1) * 16 + g4 * 4;
#pragma unroll
        for (int r = 0; r < 4; ++r)
          if (((ww >> (bb + r)) & 1u) == 0u) sacc[nt][r] = -1e9f;
      }
    }

    // ---- row max: lane-local 16 + 2 shfl ----
    float mx = sacc[0][0];
#pragma unroll
    for (int nt = 0; nt < 4; ++nt)
#pragma unroll
      for (int r = 0; r < 4; ++r) mx = fmaxf(mx, sacc[nt][r]);
    mx = fmaxf(mx, __shfl_xor(mx, 16, 64));
    mx = fmaxf(mx, __shfl_xor(mx, 32, 64));

    // ---- defer-max (THR=8 in log2 domain -> P bounded by 256) ----
    if (__any(mx > mrun + 8.f)) {
      float mnew = fmaxf(mrun, mx);
      float sc = exp2x(mrun - mnew);   // exp2(-inf)=0 on first tile
      lrun *= sc;
      mrun = mnew;
      float scO[4];
#pragma unroll
      for (int r = 0; r < 4; ++r)
        scO[r] = __shfl(sc, (lane & 48) | (((lane & 48) >> 2) + r), 64);
#pragma unroll
      for (int dt = 0; dt < 8; ++dt)
#pragma unroll
        for (int r = 0; r < 4; ++r) oacc[dt][r] *= scO[r];
    }

    // ---- exp2 + row sum (lane-local + 2 shfl) ----
    float p[4][4];
    float s0 = 0.f;
#pragma unroll
    for (int nt = 0; nt < 4; ++nt)
#pragma unroll
      for (int r = 0; r < 4; ++r) {
        float pv = exp2x(sacc[nt][r] - mrun);
        p[nt][r] = pv;
        s0 += pv;
      }
    s0 += __shfl_xor(s0, 16, 64);
    s0 += __shfl_xor(s0, 32, 64);
    lrun += s0;

    // ---- P -> PV A-frags in-register (cvt_pk + 12 shfl) ----
    unsigned int paw[2][4];
#pragma unroll
    for (int h2 = 0; h2 < 2; ++h2) {
      unsigned int D0a = cvtpk(p[2 * h2][0], p[2 * h2][1]);
      unsigned int D1a = cvtpk(p[2 * h2][2], p[2 * h2][3]);
      unsigned int D0b = cvtpk(p[2 * h2 + 1][0], p[2 * h2 + 1][1]);
      unsigned int D1b = cvtpk(p[2 * h2 + 1][2], p[2 * h2 + 1][3]);
      unsigned int r1 = __shfl_xor(g4 < 2 ? D0a : D0b, 16, 64);
      unsigned int r2 = __shfl_xor(g4 < 2 ? D1a : D1b, 16, 64);
      unsigned int r3 = __shfl_xor(g4 == 0 ? D0b : D0a, 32, 64);
      unsigned int r4 = __shfl_xor(g4 == 0 ? D1b : D1a, 32, 64);
      unsigned int r5 = __shfl_xor(g4 == 2 ? D0a : D0b, 48, 64);
      unsigned int r6 = __shfl_xor(g4 == 2 ? D1a : D1b, 48, 64);
      paw[h2][0] = g4 == 0 ? D0a : g4 == 1 ? r5 : g4 == 2 ? r3 : r1;
      paw[h2][1] = g4 == 0 ? D1a : g4 == 1 ? r6 : g4 == 2 ? r4 : r2;
      paw[h2][2] = g4 == 0 ? r1 : g4 == 1 ? r3 : g4 == 2 ? r5 : D0b;
      paw[h2][3] = g4 == 0 ? r2 : g4 == 1 ? r4 : g4 == 2 ? r6 : D1b;
    }

    // ---- PV: O += P (16x64) @ V (64x128) ----
    __builtin_amdgcn_s_setprio(1);
#pragma unroll
    for (int h2 = 0; h2 < 2; ++h2) {
      union { unsigned int u[4]; bf16x8 v; } pau;
      pau.u[0] = paw[h2][0]; pau.u[1] = paw[h2][1];
      pau.u[2] = paw[h2][2]; pau.u[3] = paw[h2][3];
#pragma unroll
      for (int dt = 0; dt < 8; ++dt) {
        bf16x8 bv = *(const bf16x8*)(smem + vb_[h2] + dt * 2048);
        oacc[dt] = __builtin_amdgcn_mfma_f32_16x16x32_bf16(pau.v, bv, oacc[dt],
                                                           0, 0, 0);
      }
    }
    __builtin_amdgcn_s_setprio(0);

    // ---- rotate buffers (register ops only; sync is the next top barrier) ----
    bufoff ^= 16384;
#pragma unroll
    for (int kc = 0; kc < 4; ++kc) kb_[kc] ^= 16384;
#pragma unroll
    for (int h2 = 0; h2 < 2; ++h2) vb_[h2] ^= 16384;
    mcur = mnext;
  }

  // ---- epilogue: att_vec = O / l (l at lane l15=qrow; O rows at g4*4+r) ----
  float linv[4];
#pragma unroll
  for (int r = 0; r < 4; ++r)
    linv[r] = 1.f / __shfl(lrun, (lane & 48) | (((lane & 48) >> 2) + r), 64);
  unsigned short* ob =
      av + (size_t)(b * TT + i0 + g4 * 4) * EE + h * DD + l15;
#pragma unroll
  for (int dt = 0; dt < 8; ++dt)
#pragma unroll
    for (int r = 0; r < 4; ++r)
      ob[(size_t)r * EE + dt * 16] = f2b(oacc[dt][r] * linv[r]);
}

// ---------- launch ----------
extern "C" void kernel_launch(void* const* d_in, const int* in_sizes, int n_in,
                              void* d_out, int out_size, void* d_ws,
                              size_t ws_size, hipStream_t stream) {
  const float* query = (const float*)d_in[0];
  const float* key   = (const float*)d_in[1];
  const int*   mask  = (const int*)d_in[2];
  const float* Wq    = (const float*)d_in[3];
  const float* Wk    = (const float*)d_in[4];
  const float* Wv    = (const float*)d_in[5];
  const float* Wu    = (const float*)d_in[6];
  const float* bu    = (const float*)d_in[7];
  float* out = (float*)d_out;

  char* ws = (char*)d_ws;
  const size_t MB = 1024 * 1024;
  unsigned short* qbf = (unsigned short*)(ws);             // 8MB bf16 query
  unsigned short* kbf = (unsigned short*)(ws + 8 * MB);    // 8MB bf16 key
  unsigned short* Wqt = (unsigned short*)(ws + 16 * MB);   // 2MB each, N x K
  unsigned short* Wkt = (unsigned short*)(ws + 18 * MB);
  unsigned short* Wvt = (unsigned short*)(ws + 20 * MB);
  unsigned short* Wut = (unsigned short*)(ws + 22 * MB);
  unsigned short* qp  = (unsigned short*)(ws + 24 * MB);   // q proj
  unsigned short* kp  = (unsigned short*)(ws + 32 * MB);   // k proj
  unsigned short* vp  = (unsigned short*)(ws + 40 * MB);   // v proj (dead after vtrans)
  unsigned short* vtb = (unsigned short*)(ws + 48 * MB);   // v transposed
  unsigned short* av  = (unsigned short*)(ws + 56 * MB);   // attention out
  unsigned long long* mbt = (unsigned long long*)(ws + 40 * MB);  // 512KB, reuses vp

  cvt_kernel<<<4096, 256, 0, stream>>>(query, key, qbf, kbf);

  WT4 wt; wt.src[0] = Wq; wt.src[1] = Wk; wt.src[2] = Wv; wt.src[3] = Wu;
  wt.dst[0] = Wqt; wt.dst[1] = Wkt; wt.dst[2] = Wvt; wt.dst[3] = Wut;
  wt.scale[0] = 1.4426950408889634f;   // log2(e): softmax in exp2 domain
  wt.scale[1] = 1.0f; wt.scale[2] = 1.0f; wt.scale[3] = 1.0f;
  wtrans_kernel<<<dim3(32, 32, 4), dim3(32, 8), 0, stream>>>(wt);

  Gemm3 g3;
  g3.A[0] = qbf; g3.A[1] = kbf; g3.A[2] = kbf;
  g3.Bt[0] = Wqt; g3.Bt[1] = Wkt; g3.Bt[2] = Wvt;
  g3.C[0] = qp; g3.C[1] = kp; g3.C[2] = vp;
  proj_gemm_kernel<<<dim3(32, 8, 3), 256, 0, stream>>>(g3);

  vtrans_kernel<<<dim3(4, 32, 32), dim3(32, 8), 0, stream>>>(vp, vtb);

  // after vtrans, vp region is dead -> pack mask bits there
  maskpack_kernel<<<1024, 256, 0, stream>>>(mask, mbt);

  attn_kernel<<<dim3(16, 8, 4), 256, 65536, stream>>>(qp, kp, vtb, mbt, av);

  out_gemm_kernel<<<dim3(64, 8), 256, 0, stream>>>(av, Wut, out, bu);
}

// Round 11
// 115.061 us; speedup vs baseline: 1.3137x; 1.0258x over previous
//
#include <hip/hip_runtime.h>
#include <hip/hip_bf16.h>

// RelativeAttention: out = softmax_j(mask((query@Wq)·(key@Wk)^T)) @ (key@Wv) @ Wu + bu
// B=4, T=1024, E=1024, H=8, D=128. All GEMMs via bf16 MFMA (f32 accum).

typedef __attribute__((ext_vector_type(8))) short bf16x8;   // 8 bf16 (4 VGPRs)
typedef __attribute__((ext_vector_type(4))) float f32x4;    // MFMA C/D frag

static constexpr int BB = 4;
static constexpr int TT = 1024;
static constexpr int EE = 1024;
static constexpr int HH = 8;
static constexpr int DD = 128;

// ---------- helpers ----------
static __device__ __forceinline__ unsigned short f2b(float x) {
  union { float f; unsigned int u; } c; c.f = x;
  unsigned int r = c.u + 0x7fffu + ((c.u >> 16) & 1u);   // RTN-even
  return (unsigned short)(r >> 16);
}

static __device__ __forceinline__ unsigned int cvtpk(float lo, float hi) {
  unsigned int r;
  asm("v_cvt_pk_bf16_f32 %0, %1, %2" : "=v"(r) : "v"(lo), "v"(hi));
  return r;   // low16 = bf16(lo), high16 = bf16(hi)
}

static __device__ __forceinline__ float exp2x(float x) {   // 2^x, 1 instr
  float r;
  asm("v_exp_f32 %0, %1" : "=v"(r) : "v"(x));
  return r;
}

static __device__ __forceinline__ void gload_lds16(const void* g, void* l) {
  __builtin_amdgcn_global_load_lds(
      (const __attribute__((address_space(1))) unsigned int*)g,
      (__attribute__((address_space(3))) unsigned int*)l, 16, 0, 0);
}

// ---------- f32 -> bf16 convert for query & key ----------
__global__ __launch_bounds__(256) void cvt_kernel(
    const float* __restrict__ qf, const float* __restrict__ kf,
    unsigned short* __restrict__ qb, unsigned short* __restrict__ kb) {
  int i = blockIdx.x * 256 + threadIdx.x;   // each thread: 4 elements of each
  float4 a = ((const float4*)qf)[i];
  ushort4 oa; oa.x = f2b(a.x); oa.y = f2b(a.y); oa.z = f2b(a.z); oa.w = f2b(a.w);
  ((ushort4*)qb)[i] = oa;
  float4 b = ((const float4*)kf)[i];
  ushort4 ob; ob.x = f2b(b.x); ob.y = f2b(b.y); ob.z = f2b(b.z); ob.w = f2b(b.w);
  ((ushort4*)kb)[i] = ob;
}

// ---------- weight transpose-convert: W (K x N) f32 -> Wt (N x K) bf16 ----------
// scale folds log2(e) into Wq so softmax can run in exp2 domain.
struct WT4 { const float* src[4]; unsigned short* dst[4]; float scale[4]; };

__global__ __launch_bounds__(256) void wtrans_kernel(WT4 wt) {
  const float* src = wt.src[blockIdx.z];
  unsigned short* dst = wt.dst[blockIdx.z];
  const float sc = wt.scale[blockIdx.z];
  __shared__ float tile[32][33];
  int n0 = blockIdx.x * 32, k0 = blockIdx.y * 32;
  int tx = threadIdx.x, ty = threadIdx.y;   // (32, 8)
#pragma unroll
  for (int i = 0; i < 4; ++i)
    tile[ty + i * 8][tx] = src[(size_t)(k0 + ty + i * 8) * EE + n0 + tx];
  __syncthreads();
#pragma unroll
  for (int i = 0; i < 4; ++i)
    dst[(size_t)(n0 + ty + i * 8) * EE + k0 + tx] = f2b(tile[tx][ty + i * 8] * sc);
}

// ---------- V transpose: vp [b,kt, h*128+d] -> vt [b,h,d, kt] (bf16) ----------
__global__ __launch_bounds__(256) void vtrans_kernel(
    const unsigned short* __restrict__ vp, unsigned short* __restrict__ vt) {
  int bh = blockIdx.z; int b = bh >> 3, h = bh & 7;
  int d0 = blockIdx.x * 32, kt0 = blockIdx.y * 32;
  __shared__ unsigned short tile[32][33];
  int tx = threadIdx.x, ty = threadIdx.y;
#pragma unroll
  for (int i = 0; i < 4; ++i)
    tile[ty + i * 8][tx] =
        vp[(size_t)(b * TT + kt0 + ty + i * 8) * EE + h * DD + d0 + tx];
  __syncthreads();
#pragma unroll
  for (int i = 0; i < 4; ++i)
    vt[(size_t)((b * HH + h) * DD + d0 + ty + i * 8) * TT + kt0 + tx] =
        tile[tx][ty + i * 8];
}

// ---------- mask -> bitmask: mbits[row][t] bit j = (mask[row][t*64+j] != 0) ----
__global__ __launch_bounds__(256) void maskpack_kernel(
    const int* __restrict__ mask, unsigned long long* __restrict__ mbits) {
  int row = blockIdx.x * 4 + (threadIdx.x >> 6);   // row < B*TT = 4096
  int lane = threadIdx.x & 63;
  const int* mrow = mask + (size_t)row * TT;
  unsigned long long myw = 0;
#pragma unroll
  for (int jw = 0; jw < 16; ++jw) {
    unsigned long long bal = __ballot(mrow[jw * 64 + lane] != 0);
    if (lane == jw) myw = bal;
  }
  if (lane < 16) mbits[(size_t)row * 16 + lane] = myw;
}

// ---------- GEMM core (bf16 out): C[M,N] = A[M,K] @ Bt[N,K]^T ----------
// 128x128 tile, BK=64, 4 waves (2x2), T2 XOR chunk swizzle both sides (g21).
static __device__ __forceinline__ void gemm_core(
    const unsigned short* __restrict__ A, const unsigned short* __restrict__ Bt,
    unsigned short* __restrict__ Cb) {
  constexpr int K = EE, N = EE;
  __shared__ __align__(16) unsigned short As[128 * 64];
  __shared__ __align__(16) unsigned short Bs[128 * 64];
  const int tid = threadIdx.x, lane = tid & 63, w = tid >> 6;
  const int wm = w >> 1, wn = w & 1;
  const int bm = blockIdx.x, bn = blockIdx.y;
  const int g4 = lane >> 4, l15 = lane & 15;

  f32x4 acc[4][4] = {};

  for (int kt = 0; kt < K / 64; ++kt) {
    const int k0 = kt * 64;
#pragma unroll
    for (int it = 0; it < 4; ++it) {
      int idx = it * 256 + tid;           // 16B chunk id: 128 rows x 8 chunks
      int r = idx >> 3, c = (idx & 7) ^ (r & 7);
      gload_lds16(A + (size_t)(bm * 128 + r) * K + k0 + c * 8, As + idx * 8);
      gload_lds16(Bt + (size_t)(bn * 128 + r) * K + k0 + c * 8, Bs + idx * 8);
    }
    __syncthreads();
    bf16x8 af[2][4], bf[2][4];
#pragma unroll
    for (int kc2 = 0; kc2 < 2; ++kc2) {
      int co = ((kc2 * 4 + g4) ^ (l15 & 7)) * 8;   // swizzled chunk offset
#pragma unroll
      for (int i = 0; i < 4; ++i) {
        af[kc2][i] = *(const bf16x8*)(As + (wm * 64 + i * 16 + l15) * 64 + co);
        bf[kc2][i] = *(const bf16x8*)(Bs + (wn * 64 + i * 16 + l15) * 64 + co);
      }
    }
#pragma unroll
    for (int kc2 = 0; kc2 < 2; ++kc2)
#pragma unroll
      for (int i = 0; i < 4; ++i)
#pragma unroll
        for (int j = 0; j < 4; ++j)
          acc[i][j] = __builtin_amdgcn_mfma_f32_16x16x32_bf16(
              af[kc2][i], bf[kc2][j], acc[i][j], 0, 0, 0);
    __syncthreads();
  }

  // epilogue: C/D layout col=lane&15, row=(lane>>4)*4+reg
  const int rr = g4 * 4;
#pragma unroll
  for (int i = 0; i < 4; ++i)
#pragma unroll
    for (int j = 0; j < 4; ++j) {
      int row = bm * 128 + wm * 64 + i * 16 + rr;
      int col = bn * 128 + wn * 64 + j * 16 + l15;
#pragma unroll
      for (int r = 0; r < 4; ++r)
        Cb[(size_t)(row + r) * N + col] = f2b(acc[i][j][r]);
    }
}

struct Gemm3 { const unsigned short* A[3]; const unsigned short* Bt[3];
               unsigned short* C[3]; };

__global__ __launch_bounds__(256) void proj_gemm_kernel(Gemm3 g) {
  int z = blockIdx.z;
  gemm_core(g.A[z], g.Bt[z], g.C[z]);
}

// ---------- output GEMM: 64x128 tile (512 blocks -> 2 blocks/CU) ----------
__global__ __launch_bounds__(256) void out_gemm_kernel(
    const unsigned short* __restrict__ A, const unsigned short* __restrict__ Bt,
    float* __restrict__ Cf, const float* __restrict__ bias) {
  constexpr int K = EE, N = EE;
  __shared__ __align__(16) unsigned short As[64 * 32];
  __shared__ __align__(16) unsigned short Bs[128 * 32];
  const int tid = threadIdx.x, lane = tid & 63, w = tid >> 6;
  const int wm = w >> 1, wn = w & 1;
  const int bm = blockIdx.x, bn = blockIdx.y;
  const int g4 = lane >> 4, l15 = lane & 15;

  f32x4 acc[2][4] = {};

  for (int kt = 0; kt < K / 32; ++kt) {
    const int k0 = kt * 32;
    {
      int row = tid >> 2, c = tid & 3;               // A: 256 x 16B chunks
      gload_lds16(A + (size_t)(bm * 64 + row) * K + k0 + c * 8, As + tid * 8);
    }
#pragma unroll
    for (int it = 0; it < 2; ++it) {                 // B: 512 x 16B chunks
      int idx = it * 256 + tid;
      int row = idx >> 2, c = idx & 3;
      gload_lds16(Bt + (size_t)(bn * 128 + row) * K + k0 + c * 8, Bs + idx * 8);
    }
    __syncthreads();
    bf16x8 af[2], bf[4];
#pragma unroll
    for (int i = 0; i < 2; ++i)
      af[i] = *(const bf16x8*)(As + (wm * 32 + i * 16 + l15) * 32 + g4 * 8);
#pragma unroll
    for (int j = 0; j < 4; ++j)
      bf[j] = *(const bf16x8*)(Bs + (wn * 64 + j * 16 + l15) * 32 + g4 * 8);
#pragma unroll
    for (int i = 0; i < 2; ++i)
#pragma unroll
      for (int j = 0; j < 4; ++j)
        acc[i][j] = __builtin_amdgcn_mfma_f32_16x16x32_bf16(af[i], bf[j],
                                                            acc[i][j], 0, 0, 0);
    __syncthreads();
  }

  const int rr = g4 * 4;
#pragma unroll
  for (int i = 0; i < 2; ++i)
#pragma unroll
    for (int j = 0; j < 4; ++j) {
      int row = bm * 64 + wm * 32 + i * 16 + rr;
      int col = bn * 128 + wn * 64 + j * 16 + l15;
#pragma unroll
      for (int r = 0; r < 4; ++r)
        Cf[(size_t)(row + r) * N + col] = acc[i][j][r] + bias[col];
    }
}

// ---------- fused attention: in-block split-K, 8 waves, 4 waves/SIMD ----------
// Waves 0-3 (group 0) handle kt [0,512); waves 4-7 (group 1) kt [512,1024).
// Each wave owns 16 q-rows (qw = w&3), KVBLK=32, swapped QK^T, exp2 softmax,
// defer-max, u32 bitmask, XCD remap. LDS 64KB: K = dbuf x 2grp x [32][128];
// V = dbuf x shared [128][64] with chunk cols 0-3 = grp0 kt, 4-7 = grp1 kt
// (keeps 128B rows -> proven c^(row&7) swizzle, 2-way-free banks).
// Staging roles: waves 0-3 stage K (one group-half each), 4-7 stage V.
// R8 protocol: stage(t+1) at top, one __syncthreads at bottom (drains vmcnt,
// guarantees cross-wave LDS visibility). Group partials (O,m,l) merge
// in-block via LDS at the end: m*=max, a_i=exp2(m_i-m*), O=sum a_i O_i,
// l=sum a_i l_i -> exact online-softmax semantics incl. fully-masked rows.
__global__ __launch_bounds__(512, 4) void attn_kernel(
    const unsigned short* __restrict__ q, const unsigned short* __restrict__ k,
    const unsigned short* __restrict__ vt,
    const unsigned long long* __restrict__ mbits,
    unsigned short* __restrict__ av) {
  extern __shared__ __align__(16) char smem[];
  // [0,32K): K, buf*16384 + grp*8192 ; [32K,64K): V, 32768 + buf*16384

  const int tid = threadIdx.x, lane = tid & 63, w = tid >> 6;   // w 0..7
  const int grp = w >> 2, qw = w & 3;
  // ---- XCD-aware bijective remap (512 blocks = 8 XCD x 64) ----
  const int orig = blockIdx.x + 16 * blockIdx.y + 128 * blockIdx.z;
  const int qt = (orig >> 3) & 15;
  const int pair = ((orig & 7) << 2) | (orig >> 7);   // [0,32)
  const int h = pair & 7, b = pair >> 3;
  const int i0 = qt * 64 + qw * 16;
  const int g4 = lane >> 4, l15 = lane & 15;
  const int swz = (l15 & 7) << 4;

  // Q fragments (operand layout: elem row=lane&15, k=(lane>>4)*8+j)
  bf16x8 aq[4];
  {
    const unsigned short* qb =
        q + (size_t)(b * TT + i0 + l15) * EE + h * DD + g4 * 8;
#pragma unroll
    for (int kc = 0; kc < 4; ++kc) aq[kc] = *(const bf16x8*)(qb + kc * 32);
  }

  // ---- staging role (pre-swizzled source chunk, g21 involution) ----
  const unsigned short* sptr[4];
  int ldsb[4];
  size_t sadv;
  if (w < 4) {
    // K stager: group kg = w>>1, half kh = w&1; tile [32][128], 16 chunks/row
    int kg = w >> 1, kh = w & 1;
    const unsigned short* kb0 = k + (size_t)(b * TT) * EE + h * DD;
#pragma unroll
    for (int p = 0; p < 4; ++p) {
      int idx = kh * 256 + p * 64 + lane;          // [0,512) chunk in group tile
      int kr = idx >> 4, c = (idx & 15) ^ (kr & 7);
      sptr[p] = kb0 + (size_t)(kg * 512 + kr) * EE + c * 8;
      ldsb[p] = kg * 8192 + (kh * 256 + p * 64) * 16;   // wave-uniform
    }
    sadv = (size_t)32 * EE;   // +32 kt rows per tile
  } else {
    // V stager: shared [128 d][64 kt] tile; eff chunk = slot^(d&7);
    // eff<4 -> grp0 kt, eff>=4 -> grp1 kt (each 32-kt subtile)
    int vw = w - 4;
    const unsigned short* vb0 = vt + (size_t)((b * HH + h) * DD) * TT;
#pragma unroll
    for (int p = 0; p < 4; ++p) {
      int cid = vw * 256 + p * 64 + lane;          // [0,1024)
      int d = cid >> 3, slot = cid & 7, eff = slot ^ (d & 7);
      sptr[p] = vb0 + (size_t)d * TT + (eff >> 2) * 512 + (eff & 3) * 8;
      ldsb[p] = 32768 + (vw * 256 + p * 64) * 16;  // wave-uniform
    }
    sadv = 32;   // +32 kt per tile
  }

  // mask u32 words: word tau covers kt [32*tau, +32); group offset 16 words
  const unsigned* mb32 =
      (const unsigned*)mbits + ((size_t)(b * TT + i0 + l15) << 5) + grp * 16;
  unsigned mcur = mb32[0];

  // LDS read bases: K addr = bufoff + kb_[kc] + nt*4096 (krow&7 == l15&7);
  // V addr = bufoff + vb_ + dt*2048 (d&7 == l15&7)
  int kb_[4];
#pragma unroll
  for (int kc = 0; kc < 4; ++kc)
    kb_[kc] = grp * 8192 + l15 * 256 + ((kc * 64 + g4 * 16) ^ swz);
  const int vb_ = 32768 + l15 * 128 + (((grp * 4 + g4) ^ (l15 & 7)) << 4);

  // prologue: stage tile 0 into buf 0
#pragma unroll
  for (int p = 0; p < 4; ++p) gload_lds16(sptr[p], smem + ldsb[p]);
#pragma unroll
  for (int p = 0; p < 4; ++p) sptr[p] += sadv;

  f32x4 oacc[8] = {};
  float mrun = -__builtin_inff(), lrun = 0.f;   // per lane: q-row = l15

  __syncthreads();
  int bufoff = 0;

  for (int t = 0; t < 16; ++t) {
    // ---- issue next tile into the other buffer (mask word first) ----
    unsigned mnext = 0;
    if (t < 15) {
      mnext = mb32[t + 1];
      int dst = bufoff ^ 16384;
#pragma unroll
      for (int p = 0; p < 4; ++p) gload_lds16(sptr[p], smem + dst + ldsb[p]);
#pragma unroll
      for (int p = 0; p < 4; ++p) sptr[p] += sadv;
    }

    // ---- S^T = K Q^T: lane holds q-row l15, kt32 = nt*16 + g4*4 + r ----
    f32x4 sacc[2] = {};
    __builtin_amdgcn_s_setprio(1);
#pragma unroll
    for (int kc = 0; kc < 4; ++kc)
#pragma unroll
      for (int nt = 0; nt < 2; ++nt) {
        bf16x8 bk = *(const bf16x8*)(smem + bufoff + kb_[kc] + nt * 4096);
        sacc[nt] = __builtin_amdgcn_mfma_f32_16x16x32_bf16(bk, aq[kc],
                                                           sacc[nt], 0, 0, 0);
      }
    __builtin_amdgcn_s_setprio(0);

    // ---- mask: bit==0 -> -1e9 ----
#pragma unroll
    for (int nt = 0; nt < 2; ++nt)
#pragma unroll
      for (int r = 0; r < 4; ++r)
        if (((mcur >> (nt * 16 + g4 * 4 + r)) & 1u) == 0u)
          sacc[nt][r] = -1e9f;

    // ---- row max: lane-local 8 + 2 shfl ----
    float mx = sacc[0][0];
#pragma unroll
    for (int nt = 0; nt < 2; ++nt)
#pragma unroll
      for (int r = 0; r < 4; ++r) mx = fmaxf(mx, sacc[nt][r]);
    mx = fmaxf(mx, __shfl_xor(mx, 16, 64));
    mx = fmaxf(mx, __shfl_xor(mx, 32, 64));

    // ---- defer-max (THR=8 in log2 domain) ----
    if (__any(mx > mrun + 8.f)) {
      float mnew = fmaxf(mrun, mx);
      float sc = exp2x(mrun - mnew);   // exp2(-inf)=0 on first tile
      lrun *= sc;
      mrun = mnew;
      float scO[4];
#pragma unroll
      for (int r = 0; r < 4; ++r)
        scO[r] = __shfl(sc, (lane & 48) | (((lane & 48) >> 2) + r), 64);
#pragma unroll
      for (int dt = 0; dt < 8; ++dt)
#pragma unroll
        for (int r = 0; r < 4; ++r) oacc[dt][r] *= scO[r];
    }

    // ---- exp2 + row sum ----
    float p2[2][4];
    float s0 = 0.f;
#pragma unroll
    for (int nt = 0; nt < 2; ++nt)
#pragma unroll
      for (int r = 0; r < 4; ++r) {
        float pv = exp2x(sacc[nt][r] - mrun);
        p2[nt][r] = pv;
        s0 += pv;
      }
    s0 += __shfl_xor(s0, 16, 64);
    s0 += __shfl_xor(s0, 32, 64);
    lrun += s0;

    // ---- P -> PV A-frag in-register (4 cvt_pk + 6 shfl) ----
    unsigned int paw[4];
    {
      unsigned int D0a = cvtpk(p2[0][0], p2[0][1]);
      unsigned int D1a = cvtpk(p2[0][2], p2[0][3]);
      unsigned int D0b = cvtpk(p2[1][0], p2[1][1]);
      unsigned int D1b = cvtpk(p2[1][2], p2[1][3]);
      unsigned int r1 = __shfl_xor(g4 < 2 ? D0a : D0b, 16, 64);
      unsigned int r2 = __shfl_xor(g4 < 2 ? D1a : D1b, 16, 64);
      unsigned int r3 = __shfl_xor(g4 == 0 ? D0b : D0a, 32, 64);
      unsigned int r4 = __shfl_xor(g4 == 0 ? D1b : D1a, 32, 64);
      unsigned int r5 = __shfl_xor(g4 == 2 ? D0a : D0b, 48, 64);
      unsigned int r6 = __shfl_xor(g4 == 2 ? D1a : D1b, 48, 64);
      paw[0] = g4 == 0 ? D0a : g4 == 1 ? r5 : g4 == 2 ? r3 : r1;
      paw[1] = g4 == 0 ? D1a : g4 == 1 ? r6 : g4 == 2 ? r4 : r2;
      paw[2] = g4 == 0 ? r1 : g4 == 1 ? r3 : g4 == 2 ? r5 : D0b;
      paw[3] = g4 == 0 ? r2 : g4 == 1 ? r4 : g4 == 2 ? r6 : D1b;
    }

    // ---- PV: O += P (16x32) @ V (32x128) ----
    __builtin_amdgcn_s_setprio(1);
    {
      union { unsigned int u[4]; bf16x8 v; } pau;
      pau.u[0] = paw[0]; pau.u[1] = paw[1];
      pau.u[2] = paw[2]; pau.u[3] = paw[3];
#pragma unroll
      for (int dt = 0; dt < 8; ++dt) {
        bf16x8 bv = *(const bf16x8*)(smem + bufoff + vb_ + dt * 2048);
        oacc[dt] = __builtin_amdgcn_mfma_f32_16x16x32_bf16(pau.v, bv, oacc[dt],
                                                           0, 0, 0);
      }
    }
    __builtin_amdgcn_s_setprio(0);

    // ---- one barrier: drains prefetch + orders buffer reuse ----
    __syncthreads();
    bufoff ^= 16384;
    mcur = mnext;
  }

  // ---- in-block merge of the two kt-halves (last __syncthreads above
  //      guarantees all K/V reads done -> smem reusable) ----
  if (grp == 1) {
    // write O (swizzled slot = dt^(lane&7) so read-back is conflict-light)
    char* ob = smem + qw * 8192 + lane * 128;
#pragma unroll
    for (int dt = 0; dt < 8; ++dt)
      *(f32x4*)(ob + ((dt ^ (lane & 7)) * 16)) = oacc[dt];
    float* mlb = (float*)(smem + 32768 + qw * 512 + lane * 8);
    mlb[0] = mrun; mlb[1] = lrun;
  }
  __syncthreads();
  if (grp == 0) {
    const char* ob = smem + qw * 8192 + lane * 128;
    const float* mlb = (const float*)(smem + 32768 + qw * 512 + lane * 8);
    float m2 = mlb[0], l2 = mlb[1];
    float ms = fmaxf(mrun, m2);
    float a1 = exp2x(mrun - ms), a2 = exp2x(m2 - ms);
    float lt = lrun * a1 + l2 * a2;
    float a1O[4], a2O[4], linv[4];
#pragma unroll
    for (int r = 0; r < 4; ++r) {
      int src = (lane & 48) | (((lane & 48) >> 2) + r);
      a1O[r] = __shfl(a1, src, 64);
      a2O[r] = __shfl(a2, src, 64);
      linv[r] = 1.f / __shfl(lt, src, 64);
    }
    unsigned short* obp =
        av + (size_t)(b * TT + i0 + g4 * 4) * EE + h * DD + l15;
#pragma unroll
    for (int dt = 0; dt < 8; ++dt) {
      f32x4 o2 = *(const f32x4*)(ob + ((dt ^ (lane & 7)) * 16));
#pragma unroll
      for (int r = 0; r < 4; ++r)
        obp[(size_t)r * EE + dt * 16] =
            f2b((oacc[dt][r] * a1O[r] + o2[r] * a2O[r]) * linv[r]);
    }
  }
}

// ---------- launch ----------
extern "C" void kernel_launch(void* const* d_in, const int* in_sizes, int n_in,
                              void* d_out, int out_size, void* d_ws,
                              size_t ws_size, hipStream_t stream) {
  const float* query = (const float*)d_in[0];
  const float* key   = (const float*)d_in[1];
  const int*   mask  = (const int*)d_in[2];
  const float* Wq    = (const float*)d_in[3];
  const float* Wk    = (const float*)d_in[4];
  const float* Wv    = (const float*)d_in[5];
  const float* Wu    = (const float*)d_in[6];
  const float* bu    = (const float*)d_in[7];
  float* out = (float*)d_out;

  char* ws = (char*)d_ws;
  const size_t MB = 1024 * 1024;
  unsigned short* qbf = (unsigned short*)(ws);             // 8MB bf16 query
  unsigned short* kbf = (unsigned short*)(ws + 8 * MB);    // 8MB bf16 key
  unsigned short* Wqt = (unsigned short*)(ws + 16 * MB);   // 2MB each, N x K
  unsigned short* Wkt = (unsigned short*)(ws + 18 * MB);
  unsigned short* Wvt = (unsigned short*)(ws + 20 * MB);
  unsigned short* Wut = (unsigned short*)(ws + 22 * MB);
  unsigned short* qp  = (unsigned short*)(ws + 24 * MB);   // q proj
  unsigned short* kp  = (unsigned short*)(ws + 32 * MB);   // k proj
  unsigned short* vp  = (unsigned short*)(ws + 40 * MB);   // v proj (dead after vtrans)
  unsigned short* vtb = (unsigned short*)(ws + 48 * MB);   // v transposed
  unsigned short* av  = (unsigned short*)(ws + 56 * MB);   // attention out
  unsigned long long* mbt = (unsigned long long*)(ws + 40 * MB);  // 512KB, reuses vp

  cvt_kernel<<<4096, 256, 0, stream>>>(query, key, qbf, kbf);

  WT4 wt; wt.src[0] = Wq; wt.src[1] = Wk; wt.src[2] = Wv; wt.src[3] = Wu;
  wt.dst[0] = Wqt; wt.dst[1] = Wkt; wt.dst[2] = Wvt; wt.dst[3] = Wut;
  wt.scale[0] = 1.4426950408889634f;   // log2(e): softmax in exp2 domain
  wt.scale[1] = 1.0f; wt.scale[2] = 1.0f; wt.scale[3] = 1.0f;
  wtrans_kernel<<<dim3(32, 32, 4), dim3(32, 8), 0, stream>>>(wt);

  Gemm3 g3;
  g3.A[0] = qbf; g3.A[1] = kbf; g3.A[2] = kbf;
  g3.Bt[0] = Wqt; g3.Bt[1] = Wkt; g3.Bt[2] = Wvt;
  g3.C[0] = qp; g3.C[1] = kp; g3.C[2] = vp;
  proj_gemm_kernel<<<dim3(32, 8, 3), 256, 0, stream>>>(g3);

  vtrans_kernel<<<dim3(4, 32, 32), dim3(32, 8), 0, stream>>>(vp, vtb);

  // after vtrans, vp region is dead -> pack mask bits there
  maskpack_kernel<<<1024, 256, 0, stream>>>(mask, mbt);

  attn_kernel<<<dim3(16, 8, 4), 512, 65536, stream>>>(qp, kp, vtb, mbt, av);

  out_gemm_kernel<<<dim3(64, 8), 256, 0, stream>>>(av, Wut, out, bu);
}

// Round 13
// 107.234 us; speedup vs baseline: 1.4096x; 1.0730x over previous
//
#include <hip/hip_runtime.h>
#include <hip/hip_bf16.h>

// RelativeAttention: out = softmax_j(mask((query@Wq)·(key@Wk)^T)) @ (key@Wv) @ Wu + bu
// B=4, T=1024, E=1024, H=8, D=128. All GEMMs via bf16 MFMA (f32 accum).

typedef __attribute__((ext_vector_type(8))) short bf16x8;   // 8 bf16 (4 VGPRs)
typedef __attribute__((ext_vector_type(4))) float f32x4;    // MFMA C/D frag

static constexpr int BB = 4;
static constexpr int TT = 1024;
static constexpr int EE = 1024;
static constexpr int HH = 8;
static constexpr int DD = 128;

// ---------- helpers ----------
static __device__ __forceinline__ unsigned short f2b(float x) {
  union { float f; unsigned int u; } c; c.f = x;
  unsigned int r = c.u + 0x7fffu + ((c.u >> 16) & 1u);   // RTN-even
  return (unsigned short)(r >> 16);
}

static __device__ __forceinline__ unsigned int cvtpk(float lo, float hi) {
  unsigned int r;
  asm("v_cvt_pk_bf16_f32 %0, %1, %2" : "=v"(r) : "v"(lo), "v"(hi));
  return r;   // low16 = bf16(lo), high16 = bf16(hi)
}

static __device__ __forceinline__ float exp2x(float x) {   // 2^x, 1 instr
  float r;
  asm("v_exp_f32 %0, %1" : "=v"(r) : "v"(x));
  return r;
}

static __device__ __forceinline__ void gload_lds16(const void* g, void* l) {
  __builtin_amdgcn_global_load_lds(
      (const __attribute__((address_space(1))) unsigned int*)g,
      (__attribute__((address_space(3))) unsigned int*)l, 16, 0, 0);
}

// ---------- prep: cvt (blocks 0-4095) + weight transpose (4096-8191) ----------
struct PrepArgs {
  const float* qf; const float* kf;
  unsigned short* qb; unsigned short* kb;
  const float* wsrc[4]; unsigned short* wdst[4]; float wscale[4];
};

__global__ __launch_bounds__(256) void prep_kernel(PrepArgs a) {
  __shared__ float tile[32][33];
  const int bid = blockIdx.x, tid = threadIdx.x;
  if (bid < 4096) {
    // f32 -> bf16 convert of query & key (4 elems each per thread)
    int i = bid * 256 + tid;
    float4 va = ((const float4*)a.qf)[i];
    ushort4 oa; oa.x = f2b(va.x); oa.y = f2b(va.y);
    oa.z = f2b(va.z); oa.w = f2b(va.w);
    ((ushort4*)a.qb)[i] = oa;
    float4 vb = ((const float4*)a.kf)[i];
    ushort4 ob; ob.x = f2b(vb.x); ob.y = f2b(vb.y);
    ob.z = f2b(vb.z); ob.w = f2b(vb.w);
    ((ushort4*)a.kb)[i] = ob;
  } else {
    // W (K x N) f32 -> Wt (N x K) bf16, scaled (log2e folded into Wq)
    int g = bid - 4096;
    int wz = g >> 10, rem = g & 1023;
    int n0 = (rem & 31) * 32, k0 = (rem >> 5) * 32;
    const float* src = a.wsrc[wz];
    unsigned short* dst = a.wdst[wz];
    const float sc = a.wscale[wz];
    int tx = tid & 31, ty = tid >> 5;
#pragma unroll
    for (int i = 0; i < 4; ++i)
      tile[ty + i * 8][tx] = src[(size_t)(k0 + ty + i * 8) * EE + n0 + tx];
    __syncthreads();
#pragma unroll
    for (int i = 0; i < 4; ++i)
      dst[(size_t)(n0 + ty + i * 8) * EE + k0 + tx] =
          f2b(tile[tx][ty + i * 8] * sc);
  }
}

// ---------- vtrans (blocks 0-4095) + maskpack (4096-5119) ----------
__global__ __launch_bounds__(256) void vtrans_mask_kernel(
    const unsigned short* __restrict__ vp, unsigned short* __restrict__ vt,
    const int* __restrict__ mask, unsigned long long* __restrict__ mbits) {
  __shared__ unsigned short tile[32][33];
  const int bid = blockIdx.x, tid = threadIdx.x;
  if (bid < 4096) {
    // vp [b,kt, h*128+d] -> vt [b,h,d, kt]
    int x = bid & 3, y = (bid >> 2) & 31, z = bid >> 7;
    int b = z >> 3, h = z & 7;
    int d0 = x * 32, kt0 = y * 32;
    int tx = tid & 31, ty = tid >> 5;
#pragma unroll
    for (int i = 0; i < 4; ++i)
      tile[ty + i * 8][tx] =
          vp[(size_t)(b * TT + kt0 + ty + i * 8) * EE + h * DD + d0 + tx];
    __syncthreads();
#pragma unroll
    for (int i = 0; i < 4; ++i)
      vt[(size_t)((b * HH + h) * DD + d0 + ty + i * 8) * TT + kt0 + tx] =
          tile[tx][ty + i * 8];
  } else {
    // mbits[row][t] bit j = (mask[row][t*64+j] != 0)
    int row = (bid - 4096) * 4 + (tid >> 6);
    int lane = tid & 63;
    const int* mrow = mask + (size_t)row * TT;
    unsigned long long myw = 0;
#pragma unroll
    for (int jw = 0; jw < 16; ++jw) {
      unsigned long long bal = __ballot(mrow[jw * 64 + lane] != 0);
      if (lane == jw) myw = bal;
    }
    if (lane < 16) mbits[(size_t)row * 16 + lane] = myw;
  }
}

// ---------- GEMM core (bf16 out): C[M,N] = A[M,K] @ Bt[N,K]^T ----------
// 128x128 tile, BK=64, 4 waves (2x2), T2 XOR chunk swizzle both sides (g21).
static __device__ __forceinline__ void gemm_core(
    const unsigned short* __restrict__ A, const unsigned short* __restrict__ Bt,
    unsigned short* __restrict__ Cb) {
  constexpr int K = EE, N = EE;
  __shared__ __align__(16) unsigned short As[128 * 64];
  __shared__ __align__(16) unsigned short Bs[128 * 64];
  const int tid = threadIdx.x, lane = tid & 63, w = tid >> 6;
  const int wm = w >> 1, wn = w & 1;
  const int bm = blockIdx.x, bn = blockIdx.y;
  const int g4 = lane >> 4, l15 = lane & 15;

  f32x4 acc[4][4] = {};

  for (int kt = 0; kt < K / 64; ++kt) {
    const int k0 = kt * 64;
#pragma unroll
    for (int it = 0; it < 4; ++it) {
      int idx = it * 256 + tid;           // 16B chunk id: 128 rows x 8 chunks
      int r = idx >> 3, c = (idx & 7) ^ (r & 7);
      gload_lds16(A + (size_t)(bm * 128 + r) * K + k0 + c * 8, As + idx * 8);
      gload_lds16(Bt + (size_t)(bn * 128 + r) * K + k0 + c * 8, Bs + idx * 8);
    }
    __syncthreads();
    bf16x8 af[2][4], bf[2][4];
#pragma unroll
    for (int kc2 = 0; kc2 < 2; ++kc2) {
      int co = ((kc2 * 4 + g4) ^ (l15 & 7)) * 8;   // swizzled chunk offset
#pragma unroll
      for (int i = 0; i < 4; ++i) {
        af[kc2][i] = *(const bf16x8*)(As + (wm * 64 + i * 16 + l15) * 64 + co);
        bf[kc2][i] = *(const bf16x8*)(Bs + (wn * 64 + i * 16 + l15) * 64 + co);
      }
    }
#pragma unroll
    for (int kc2 = 0; kc2 < 2; ++kc2)
#pragma unroll
      for (int i = 0; i < 4; ++i)
#pragma unroll
        for (int j = 0; j < 4; ++j)
          acc[i][j] = __builtin_amdgcn_mfma_f32_16x16x32_bf16(
              af[kc2][i], bf[kc2][j], acc[i][j], 0, 0, 0);
    __syncthreads();
  }

  // epilogue: C/D layout col=lane&15, row=(lane>>4)*4+reg
  const int rr = g4 * 4;
#pragma unroll
  for (int i = 0; i < 4; ++i)
#pragma unroll
    for (int j = 0; j < 4; ++j) {
      int row = bm * 128 + wm * 64 + i * 16 + rr;
      int col = bn * 128 + wn * 64 + j * 16 + l15;
#pragma unroll
      for (int r = 0; r < 4; ++r)
        Cb[(size_t)(row + r) * N + col] = f2b(acc[i][j][r]);
    }
}

struct Gemm3 { const unsigned short* A[3]; const unsigned short* Bt[3];
               unsigned short* C[3]; };

__global__ __launch_bounds__(256) void proj_gemm_kernel(Gemm3 g) {
  int z = blockIdx.z;
  gemm_core(g.A[z], g.Bt[z], g.C[z]);
}

// ---------- output GEMM: 64x128 tile, BK=64 + swizzle (proj structure) ----------
__global__ __launch_bounds__(256) void out_gemm_kernel(
    const unsigned short* __restrict__ A, const unsigned short* __restrict__ Bt,
    float* __restrict__ Cf, const float* __restrict__ bias) {
  constexpr int K = EE, N = EE;
  __shared__ __align__(16) unsigned short As[64 * 64];    // 8KB
  __shared__ __align__(16) unsigned short Bs[128 * 64];   // 16KB
  const int tid = threadIdx.x, lane = tid & 63, w = tid >> 6;
  const int wm = w >> 1, wn = w & 1;
  const int bm = blockIdx.x, bn = blockIdx.y;
  const int g4 = lane >> 4, l15 = lane & 15;

  f32x4 acc[2][4] = {};

  for (int kt = 0; kt < K / 64; ++kt) {
    const int k0 = kt * 64;
#pragma unroll
    for (int it = 0; it < 2; ++it) {                 // A: 512 chunks
      int idx = it * 256 + tid;
      int r = idx >> 3, c = (idx & 7) ^ (r & 7);
      gload_lds16(A + (size_t)(bm * 64 + r) * K + k0 + c * 8, As + idx * 8);
    }
#pragma unroll
    for (int it = 0; it < 4; ++it) {                 // B: 1024 chunks
      int idx = it * 256 + tid;
      int r = idx >> 3, c = (idx & 7) ^ (r & 7);
      gload_lds16(Bt + (size_t)(bn * 128 + r) * K + k0 + c * 8, Bs + idx * 8);
    }
    __syncthreads();
    bf16x8 af[2][2], bf[2][4];
#pragma unroll
    for (int kc2 = 0; kc2 < 2; ++kc2) {
      int co = ((kc2 * 4 + g4) ^ (l15 & 7)) * 8;
#pragma unroll
      for (int i = 0; i < 2; ++i)
        af[kc2][i] = *(const bf16x8*)(As + (wm * 32 + i * 16 + l15) * 64 + co);
#pragma unroll
      for (int j = 0; j < 4; ++j)
        bf[kc2][j] = *(const bf16x8*)(Bs + (wn * 64 + j * 16 + l15) * 64 + co);
    }
#pragma unroll
    for (int kc2 = 0; kc2 < 2; ++kc2)
#pragma unroll
      for (int i = 0; i < 2; ++i)
#pragma unroll
        for (int j = 0; j < 4; ++j)
          acc[i][j] = __builtin_amdgcn_mfma_f32_16x16x32_bf16(
              af[kc2][i], bf[kc2][j], acc[i][j], 0, 0, 0);
    __syncthreads();
  }

  const int rr = g4 * 4;
#pragma unroll
  for (int i = 0; i < 2; ++i)
#pragma unroll
    for (int j = 0; j < 4; ++j) {
      int row = bm * 64 + wm * 32 + i * 16 + rr;
      int col = bn * 128 + wn * 64 + j * 16 + l15;
#pragma unroll
      for (int r = 0; r < 4; ++r)
        Cf[(size_t)(row + r) * N + col] = acc[i][j][r] + bias[col];
    }
}

// ---------- fused attention: in-block split-K, 8 waves, 4 waves/SIMD ----------
// R11-verified structure (shfl-based reductions). Waves 0-3 (group 0) handle
// kt [0,512); waves 4-7 (group 1) kt [512,1024). Each wave owns 16 q-rows,
// KVBLK=32, swapped QK^T, exp2 softmax, defer-max, u32 bitmask, XCD remap.
// LDS 64KB: K = dbuf x 2grp x [32][128]; V = dbuf x shared [128][64].
// Group partials merge in-block via LDS at the end.
__global__ __launch_bounds__(512, 4) void attn_kernel(
    const unsigned short* __restrict__ q, const unsigned short* __restrict__ k,
    const unsigned short* __restrict__ vt,
    const unsigned long long* __restrict__ mbits,
    unsigned short* __restrict__ av) {
  extern __shared__ __align__(16) char smem[];
  // [0,32K): K, buf*16384 + grp*8192 ; [32K,64K): V, 32768 + buf*16384

  const int tid = threadIdx.x, lane = tid & 63, w = tid >> 6;   // w 0..7
  const int grp = w >> 2, qw = w & 3;
  // ---- XCD-aware bijective remap (512 blocks = 8 XCD x 64) ----
  const int orig = blockIdx.x + 16 * blockIdx.y + 128 * blockIdx.z;
  const int qt = (orig >> 3) & 15;
  const int pair = ((orig & 7) << 2) | (orig >> 7);   // [0,32)
  const int h = pair & 7, b = pair >> 3;
  const int i0 = qt * 64 + qw * 16;
  const int g4 = lane >> 4, l15 = lane & 15;
  const int swz = (l15 & 7) << 4;

  // Q fragments (operand layout: elem row=lane&15, k=(lane>>4)*8+j)
  bf16x8 aq[4];
  {
    const unsigned short* qb =
        q + (size_t)(b * TT + i0 + l15) * EE + h * DD + g4 * 8;
#pragma unroll
    for (int kc = 0; kc < 4; ++kc) aq[kc] = *(const bf16x8*)(qb + kc * 32);
  }

  // ---- staging role (pre-swizzled source chunk, g21 involution) ----
  const unsigned short* sptr[4];
  int ldsb[4];
  size_t sadv;
  if (w < 4) {
    int kg = w >> 1, kh = w & 1;
    const unsigned short* kb0 = k + (size_t)(b * TT) * EE + h * DD;
#pragma unroll
    for (int p = 0; p < 4; ++p) {
      int idx = kh * 256 + p * 64 + lane;
      int kr = idx >> 4, c = (idx & 15) ^ (kr & 7);
      sptr[p] = kb0 + (size_t)(kg * 512 + kr) * EE + c * 8;
      ldsb[p] = kg * 8192 + (kh * 256 + p * 64) * 16;
    }
    sadv = (size_t)32 * EE;
  } else {
    int vw = w - 4;
    const unsigned short* vb0 = vt + (size_t)((b * HH + h) * DD) * TT;
#pragma unroll
    for (int p = 0; p < 4; ++p) {
      int cid = vw * 256 + p * 64 + lane;
      int d = cid >> 3, slot = cid & 7, eff = slot ^ (d & 7);
      sptr[p] = vb0 + (size_t)d * TT + (eff >> 2) * 512 + (eff & 3) * 8;
      ldsb[p] = 32768 + (vw * 256 + p * 64) * 16;
    }
    sadv = 32;
  }

  // mask u32 words: word tau covers kt [32*tau, +32); group offset 16 words
  const unsigned* mb32 =
      (const unsigned*)mbits + ((size_t)(b * TT + i0 + l15) << 5) + grp * 16;
  unsigned mcur = mb32[0];

  int kb_[4];
#pragma unroll
  for (int kc = 0; kc < 4; ++kc)
    kb_[kc] = grp * 8192 + l15 * 256 + ((kc * 64 + g4 * 16) ^ swz);
  const int vb_ = 32768 + l15 * 128 + (((grp * 4 + g4) ^ (l15 & 7)) << 4);

  // prologue: stage tile 0 into buf 0
#pragma unroll
  for (int p = 0; p < 4; ++p) gload_lds16(sptr[p], smem + ldsb[p]);
#pragma unroll
  for (int p = 0; p < 4; ++p) sptr[p] += sadv;

  f32x4 oacc[8] = {};
  float mrun = -__builtin_inff(), lrun = 0.f;   // per lane: q-row = l15

  __syncthreads();
  int bufoff = 0;

  for (int t = 0; t < 16; ++t) {
    // ---- issue next tile into the other buffer (mask word first) ----
    unsigned mnext = 0;
    if (t < 15) {
      mnext = mb32[t + 1];
      int dst = bufoff ^ 16384;
#pragma unroll
      for (int p = 0; p < 4; ++p) gload_lds16(sptr[p], smem + dst + ldsb[p]);
#pragma unroll
      for (int p = 0; p < 4; ++p) sptr[p] += sadv;
    }

    // ---- S^T = K Q^T: lane holds q-row l15, kt32 = nt*16 + g4*4 + r ----
    f32x4 sacc[2] = {};
    __builtin_amdgcn_s_setprio(1);
#pragma unroll
    for (int kc = 0; kc < 4; ++kc)
#pragma unroll
      for (int nt = 0; nt < 2; ++nt) {
        bf16x8 bk = *(const bf16x8*)(smem + bufoff + kb_[kc] + nt * 4096);
        sacc[nt] = __builtin_amdgcn_mfma_f32_16x16x32_bf16(bk, aq[kc],
                                                           sacc[nt], 0, 0, 0);
      }
    __builtin_amdgcn_s_setprio(0);

    // ---- mask: bit==0 -> -1e9 ----
#pragma unroll
    for (int nt = 0; nt < 2; ++nt)
#pragma unroll
      for (int r = 0; r < 4; ++r)
        if (((mcur >> (nt * 16 + g4 * 4 + r)) & 1u) == 0u)
          sacc[nt][r] = -1e9f;

    // ---- row max: lane-local 8 + 2 shfl ----
    float mx = sacc[0][0];
#pragma unroll
    for (int nt = 0; nt < 2; ++nt)
#pragma unroll
      for (int r = 0; r < 4; ++r) mx = fmaxf(mx, sacc[nt][r]);
    mx = fmaxf(mx, __shfl_xor(mx, 16, 64));
    mx = fmaxf(mx, __shfl_xor(mx, 32, 64));

    // ---- defer-max (THR=8 in log2 domain) ----
    if (__any(mx > mrun + 8.f)) {
      float mnew = fmaxf(mrun, mx);
      float sc = exp2x(mrun - mnew);   // exp2(-inf)=0 on first tile
      lrun *= sc;
      mrun = mnew;
      float scO[4];
#pragma unroll
      for (int r = 0; r < 4; ++r)
        scO[r] = __shfl(sc, (lane & 48) | (((lane & 48) >> 2) + r), 64);
#pragma unroll
      for (int dt = 0; dt < 8; ++dt)
#pragma unroll
        for (int r = 0; r < 4; ++r) oacc[dt][r] *= scO[r];
    }

    // ---- exp2 + row sum ----
    float p2[2][4];
    float s0 = 0.f;
#pragma unroll
    for (int nt = 0; nt < 2; ++nt)
#pragma unroll
      for (int r = 0; r < 4; ++r) {
        float pv = exp2x(sacc[nt][r] - mrun);
        p2[nt][r] = pv;
        s0 += pv;
      }
    s0 += __shfl_xor(s0, 16, 64);
    s0 += __shfl_xor(s0, 32, 64);
    lrun += s0;

    // ---- P -> PV A-frag in-register (4 cvt_pk + 6 shfl) ----
    unsigned int paw[4];
    {
      unsigned int D0a = cvtpk(p2[0][0], p2[0][1]);
      unsigned int D1a = cvtpk(p2[0][2], p2[0][3]);
      unsigned int D0b = cvtpk(p2[1][0], p2[1][1]);
      unsigned int D1b = cvtpk(p2[1][2], p2[1][3]);
      unsigned int r1 = __shfl_xor(g4 < 2 ? D0a : D0b, 16, 64);
      unsigned int r2 = __shfl_xor(g4 < 2 ? D1a : D1b, 16, 64);
      unsigned int r3 = __shfl_xor(g4 == 0 ? D0b : D0a, 32, 64);
      unsigned int r4 = __shfl_xor(g4 == 0 ? D1b : D1a, 32, 64);
      unsigned int r5 = __shfl_xor(g4 == 2 ? D0a : D0b, 48, 64);
      unsigned int r6 = __shfl_xor(g4 == 2 ? D1a : D1b, 48, 64);
      paw[0] = g4 == 0 ? D0a : g4 == 1 ? r5 : g4 == 2 ? r3 : r1;
      paw[1] = g4 == 0 ? D1a : g4 == 1 ? r6 : g4 == 2 ? r4 : r2;
      paw[2] = g4 == 0 ? r1 : g4 == 1 ? r3 : g4 == 2 ? r5 : D0b;
      paw[3] = g4 == 0 ? r2 : g4 == 1 ? r4 : g4 == 2 ? r6 : D1b;
    }

    // ---- PV: O += P (16x32) @ V (32x128) ----
    __builtin_amdgcn_s_setprio(1);
    {
      union { unsigned int u[4]; bf16x8 v; } pau;
      pau.u[0] = paw[0]; pau.u[1] = paw[1];
      pau.u[2] = paw[2]; pau.u[3] = paw[3];
#pragma unroll
      for (int dt = 0; dt < 8; ++dt) {
        bf16x8 bv = *(const bf16x8*)(smem + bufoff + vb_ + dt * 2048);
        oacc[dt] = __builtin_amdgcn_mfma_f32_16x16x32_bf16(pau.v, bv, oacc[dt],
                                                           0, 0, 0);
      }
    }
    __builtin_amdgcn_s_setprio(0);

    // ---- one barrier: drains prefetch + orders buffer reuse ----
    __syncthreads();
    bufoff ^= 16384;
    mcur = mnext;
  }

  // ---- in-block merge of the two kt-halves ----
  if (grp == 1) {
    char* ob = smem + qw * 8192 + lane * 128;
#pragma unroll
    for (int dt = 0; dt < 8; ++dt)
      *(f32x4*)(ob + ((dt ^ (lane & 7)) * 16)) = oacc[dt];
    float* mlb = (float*)(smem + 32768 + qw * 512 + lane * 8);
    mlb[0] = mrun; mlb[1] = lrun;
  }
  __syncthreads();
  if (grp == 0) {
    const char* ob = smem + qw * 8192 + lane * 128;
    const float* mlb = (const float*)(smem + 32768 + qw * 512 + lane * 8);
    float m2 = mlb[0], l2 = mlb[1];
    float ms = fmaxf(mrun, m2);
    float a1 = exp2x(mrun - ms), a2 = exp2x(m2 - ms);
    float lt = lrun * a1 + l2 * a2;
    float a1O[4], a2O[4], linv[4];
#pragma unroll
    for (int r = 0; r < 4; ++r) {
      int src = (lane & 48) | (((lane & 48) >> 2) + r);
      a1O[r] = __shfl(a1, src, 64);
      a2O[r] = __shfl(a2, src, 64);
      linv[r] = 1.f / __shfl(lt, src, 64);
    }
    unsigned short* obp =
        av + (size_t)(b * TT + i0 + g4 * 4) * EE + h * DD + l15;
#pragma unroll
    for (int dt = 0; dt < 8; ++dt) {
      f32x4 o2 = *(const f32x4*)(ob + ((dt ^ (lane & 7)) * 16));
#pragma unroll
      for (int r = 0; r < 4; ++r)
        obp[(size_t)r * EE + dt * 16] =
            f2b((oacc[dt][r] * a1O[r] + o2[r] * a2O[r]) * linv[r]);
    }
  }
}

// ---------- launch ----------
extern "C" void kernel_launch(void* const* d_in, const int* in_sizes, int n_in,
                              void* d_out, int out_size, void* d_ws,
                              size_t ws_size, hipStream_t stream) {
  const float* query = (const float*)d_in[0];
  const float* key   = (const float*)d_in[1];
  const int*   mask  = (const int*)d_in[2];
  const float* Wq    = (const float*)d_in[3];
  const float* Wk    = (const float*)d_in[4];
  const float* Wv    = (const float*)d_in[5];
  const float* Wu    = (const float*)d_in[6];
  const float* bu    = (const float*)d_in[7];
  float* out = (float*)d_out;

  char* ws = (char*)d_ws;
  const size_t MB = 1024 * 1024;
  unsigned short* qbf = (unsigned short*)(ws);             // 8MB bf16 query
  unsigned short* kbf = (unsigned short*)(ws + 8 * MB);    // 8MB bf16 key
  unsigned short* Wqt = (unsigned short*)(ws + 16 * MB);   // 2MB each, N x K
  unsigned short* Wkt = (unsigned short*)(ws + 18 * MB);
  unsigned short* Wvt = (unsigned short*)(ws + 20 * MB);
  unsigned short* Wut = (unsigned short*)(ws + 22 * MB);
  unsigned short* qp  = (unsigned short*)(ws + 24 * MB);   // q proj
  unsigned short* kp  = (unsigned short*)(ws + 32 * MB);   // k proj
  unsigned short* vp  = (unsigned short*)(ws + 40 * MB);   // v proj
  unsigned short* vtb = (unsigned short*)(ws + 48 * MB);   // v transposed
  unsigned short* av  = (unsigned short*)(ws + 56 * MB);   // attention out
  // mask bits live in the qbf region (dead after proj_gemm; maskpack runs
  // inside the vtrans launch, strictly after proj_gemm).
  unsigned long long* mbt = (unsigned long long*)(ws);     // 512KB

  PrepArgs pa;
  pa.qf = query; pa.kf = key; pa.qb = qbf; pa.kb = kbf;
  pa.wsrc[0] = Wq; pa.wsrc[1] = Wk; pa.wsrc[2] = Wv; pa.wsrc[3] = Wu;
  pa.wdst[0] = Wqt; pa.wdst[1] = Wkt; pa.wdst[2] = Wvt; pa.wdst[3] = Wut;
  pa.wscale[0] = 1.4426950408889634f;   // log2(e): softmax in exp2 domain
  pa.wscale[1] = 1.0f; pa.wscale[2] = 1.0f; pa.wscale[3] = 1.0f;
  prep_kernel<<<8192, 256, 0, stream>>>(pa);

  Gemm3 g3;
  g3.A[0] = qbf; g3.A[1] = kbf; g3.A[2] = kbf;
  g3.Bt[0] = Wqt; g3.Bt[1] = Wkt; g3.Bt[2] = Wvt;
  g3.C[0] = qp; g3.C[1] = kp; g3.C[2] = vp;
  proj_gemm_kernel<<<dim3(32, 8, 3), 256, 0, stream>>>(g3);

  vtrans_mask_kernel<<<5120, 256, 0, stream>>>(vp, vtb, mask, mbt);

  attn_kernel<<<dim3(16, 8, 4), 512, 65536, stream>>>(qp, kp, vtb, mbt, av);

  out_gemm_kernel<<<dim3(64, 8), 256, 0, stream>>>(av, Wut, out, bu);
}

// Round 15
// 106.166 us; speedup vs baseline: 1.4237x; 1.0101x over previous
//
#include <hip/hip_runtime.h>
#include <hip/hip_bf16.h>

// RelativeAttention: out = softmax_j(mask((query@Wq)·(key@Wk)^T)) @ (key@Wv) @ Wu + bu
// B=4, T=1024, E=1024, H=8, D=128. All GEMMs via bf16 MFMA (f32 accum).

typedef __attribute__((ext_vector_type(8))) short bf16x8;   // 8 bf16 (4 VGPRs)
typedef __attribute__((ext_vector_type(4))) float f32x4;    // MFMA C/D frag

static constexpr int BB = 4;
static constexpr int TT = 1024;
static constexpr int EE = 1024;
static constexpr int HH = 8;
static constexpr int DD = 128;

// ---------- helpers ----------
static __device__ __forceinline__ unsigned short f2b(float x) {
  union { float f; unsigned int u; } c; c.f = x;
  unsigned int r = c.u + 0x7fffu + ((c.u >> 16) & 1u);   // RTN-even
  return (unsigned short)(r >> 16);
}

static __device__ __forceinline__ unsigned int cvtpk(float lo, float hi) {
  unsigned int r;
  asm("v_cvt_pk_bf16_f32 %0, %1, %2" : "=v"(r) : "v"(lo), "v"(hi));
  return r;   // low16 = bf16(lo), high16 = bf16(hi)
}

static __device__ __forceinline__ float exp2x(float x) {   // 2^x, 1 instr
  float r;
  asm("v_exp_f32 %0, %1" : "=v"(r) : "v"(x));
  return r;
}

// ---- permlane swap helpers (VALU ~4cyc, replaces ds_bpermute shfl ~60cyc) ----
// R12 post-mortem: both asm operands derived from the SAME SSA value let the
// allocator put them in ONE physical VGPR -> in-place scramble. Fix: the
// second operand comes from an OPAQUE v_mov (fresh unknowable value -> the
// allocator cannot coalesce it with the first).
// Semantics (ISA): swap16: vdst rows 1,3 <-> vsrc rows 0,2; with d=s=x:
//   a'={x0,x0,x2,x2}, b'={x1,x1,x3,x3}.  swap32: a'={xlo,xlo}, b'={xhi,xhi}.
static __device__ __forceinline__ unsigned opq(unsigned x) {
  unsigned y;
  asm("v_mov_b32 %0, %1" : "=v"(y) : "v"(x));
  return y;
}
static __device__ __forceinline__ float qred_max(float x) {
  unsigned a = __float_as_uint(x), b = opq(a);
  asm("v_permlane16_swap_b32 %0, %1" : "+v"(a), "+v"(b));
  float m = fmaxf(__uint_as_float(a), __uint_as_float(b));   // pairs 01 / 23
  unsigned c = __float_as_uint(m), d = opq(c);
  asm("v_permlane32_swap_b32 %0, %1" : "+v"(c), "+v"(d));
  return fmaxf(__uint_as_float(c), __uint_as_float(d));      // all 4 groups
}
static __device__ __forceinline__ float qred_sum(float x) {
  unsigned a = __float_as_uint(x), b = opq(a);
  asm("v_permlane16_swap_b32 %0, %1" : "+v"(a), "+v"(b));
  float s = __uint_as_float(a) + __uint_as_float(b);
  unsigned c = __float_as_uint(s), d = opq(c);
  asm("v_permlane32_swap_b32 %0, %1" : "+v"(c), "+v"(d));
  return __uint_as_float(c) + __uint_as_float(d);
}
static __device__ __forceinline__ unsigned lx16(unsigned v, int lane) { // v[l^16]
  unsigned a = v, b = opq(v);
  asm("v_permlane16_swap_b32 %0, %1" : "+v"(a), "+v"(b));
  return (lane & 16) ? a : b;
}
static __device__ __forceinline__ unsigned lx32(unsigned v, int lane) { // v[l^32]
  unsigned a = v, b = opq(v);
  asm("v_permlane32_swap_b32 %0, %1" : "+v"(a), "+v"(b));
  return (lane & 32) ? a : b;
}

static __device__ __forceinline__ void gload_lds16(const void* g, void* l) {
  __builtin_amdgcn_global_load_lds(
      (const __attribute__((address_space(1))) unsigned int*)g,
      (__attribute__((address_space(3))) unsigned int*)l, 16, 0, 0);
}

// ---------- prep: cvt (blocks 0-4095) + weight transpose (4096-8191) ----------
struct PrepArgs {
  const float* qf; const float* kf;
  unsigned short* qb; unsigned short* kb;
  const float* wsrc[4]; unsigned short* wdst[4]; float wscale[4];
};

__global__ __launch_bounds__(256) void prep_kernel(PrepArgs a) {
  __shared__ float tile[32][33];
  const int bid = blockIdx.x, tid = threadIdx.x;
  if (bid < 4096) {
    // f32 -> bf16 convert of query & key (4 elems each per thread)
    int i = bid * 256 + tid;
    float4 va = ((const float4*)a.qf)[i];
    ushort4 oa; oa.x = f2b(va.x); oa.y = f2b(va.y);
    oa.z = f2b(va.z); oa.w = f2b(va.w);
    ((ushort4*)a.qb)[i] = oa;
    float4 vb = ((const float4*)a.kf)[i];
    ushort4 ob; ob.x = f2b(vb.x); ob.y = f2b(vb.y);
    ob.z = f2b(vb.z); ob.w = f2b(vb.w);
    ((ushort4*)a.kb)[i] = ob;
  } else {
    // W (K x N) f32 -> Wt (N x K) bf16, scaled (log2e folded into Wq)
    int g = bid - 4096;
    int wz = g >> 10, rem = g & 1023;
    int n0 = (rem & 31) * 32, k0 = (rem >> 5) * 32;
    const float* src = a.wsrc[wz];
    unsigned short* dst = a.wdst[wz];
    const float sc = a.wscale[wz];
    int tx = tid & 31, ty = tid >> 5;
#pragma unroll
    for (int i = 0; i < 4; ++i)
      tile[ty + i * 8][tx] = src[(size_t)(k0 + ty + i * 8) * EE + n0 + tx];
    __syncthreads();
#pragma unroll
    for (int i = 0; i < 4; ++i)
      dst[(size_t)(n0 + ty + i * 8) * EE + k0 + tx] =
          f2b(tile[tx][ty + i * 8] * sc);
  }
}

// ---------- vtrans (blocks 0-4095) + maskpack (4096-5119) ----------
__global__ __launch_bounds__(256) void vtrans_mask_kernel(
    const unsigned short* __restrict__ vp, unsigned short* __restrict__ vt,
    const int* __restrict__ mask, unsigned long long* __restrict__ mbits) {
  __shared__ unsigned short tile[32][33];
  const int bid = blockIdx.x, tid = threadIdx.x;
  if (bid < 4096) {
    // vp [b,kt, h*128+d] -> vt [b,h,d, kt]
    int x = bid & 3, y = (bid >> 2) & 31, z = bid >> 7;
    int b = z >> 3, h = z & 7;
    int d0 = x * 32, kt0 = y * 32;
    int tx = tid & 31, ty = tid >> 5;
#pragma unroll
    for (int i = 0; i < 4; ++i)
      tile[ty + i * 8][tx] =
          vp[(size_t)(b * TT + kt0 + ty + i * 8) * EE + h * DD + d0 + tx];
    __syncthreads();
#pragma unroll
    for (int i = 0; i < 4; ++i)
      vt[(size_t)((b * HH + h) * DD + d0 + ty + i * 8) * TT + kt0 + tx] =
          tile[tx][ty + i * 8];
  } else {
    // mbits[row][t] bit j = (mask[row][t*64+j] != 0)
    int row = (bid - 4096) * 4 + (tid >> 6);
    int lane = tid & 63;
    const int* mrow = mask + (size_t)row * TT;
    unsigned long long myw = 0;
#pragma unroll
    for (int jw = 0; jw < 16; ++jw) {
      unsigned long long bal = __ballot(mrow[jw * 64 + lane] != 0);
      if (lane == jw) myw = bal;
    }
    if (lane < 16) mbits[(size_t)row * 16 + lane] = myw;
  }
}

// ---------- GEMM core (bf16 out): C[M,N] = A[M,K] @ Bt[N,K]^T ----------
// 128x128 tile, BK=64, 4 waves (2x2), T2 XOR chunk swizzle both sides (g21).
static __device__ __forceinline__ void gemm_core(
    const unsigned short* __restrict__ A, const unsigned short* __restrict__ Bt,
    unsigned short* __restrict__ Cb) {
  constexpr int K = EE, N = EE;
  __shared__ __align__(16) unsigned short As[128 * 64];
  __shared__ __align__(16) unsigned short Bs[128 * 64];
  const int tid = threadIdx.x, lane = tid & 63, w = tid >> 6;
  const int wm = w >> 1, wn = w & 1;
  const int bm = blockIdx.x, bn = blockIdx.y;
  const int g4 = lane >> 4, l15 = lane & 15;

  f32x4 acc[4][4] = {};

  for (int kt = 0; kt < K / 64; ++kt) {
    const int k0 = kt * 64;
#pragma unroll
    for (int it = 0; it < 4; ++it) {
      int idx = it * 256 + tid;           // 16B chunk id: 128 rows x 8 chunks
      int r = idx >> 3, c = (idx & 7) ^ (r & 7);
      gload_lds16(A + (size_t)(bm * 128 + r) * K + k0 + c * 8, As + idx * 8);
      gload_lds16(Bt + (size_t)(bn * 128 + r) * K + k0 + c * 8, Bs + idx * 8);
    }
    __syncthreads();
    bf16x8 af[2][4], bf[2][4];
#pragma unroll
    for (int kc2 = 0; kc2 < 2; ++kc2) {
      int co = ((kc2 * 4 + g4) ^ (l15 & 7)) * 8;   // swizzled chunk offset
#pragma unroll
      for (int i = 0; i < 4; ++i) {
        af[kc2][i] = *(const bf16x8*)(As + (wm * 64 + i * 16 + l15) * 64 + co);
        bf[kc2][i] = *(const bf16x8*)(Bs + (wn * 64 + i * 16 + l15) * 64 + co);
      }
    }
#pragma unroll
    for (int kc2 = 0; kc2 < 2; ++kc2)
#pragma unroll
      for (int i = 0; i < 4; ++i)
#pragma unroll
        for (int j = 0; j < 4; ++j)
          acc[i][j] = __builtin_amdgcn_mfma_f32_16x16x32_bf16(
              af[kc2][i], bf[kc2][j], acc[i][j], 0, 0, 0);
    __syncthreads();
  }

  // epilogue: C/D layout col=lane&15, row=(lane>>4)*4+reg
  const int rr = g4 * 4;
#pragma unroll
  for (int i = 0; i < 4; ++i)
#pragma unroll
    for (int j = 0; j < 4; ++j) {
      int row = bm * 128 + wm * 64 + i * 16 + rr;
      int col = bn * 128 + wn * 64 + j * 16 + l15;
#pragma unroll
      for (int r = 0; r < 4; ++r)
        Cb[(size_t)(row + r) * N + col] = f2b(acc[i][j][r]);
    }
}

struct Gemm3 { const unsigned short* A[3]; const unsigned short* Bt[3];
               unsigned short* C[3]; };

__global__ __launch_bounds__(256) void proj_gemm_kernel(Gemm3 g) {
  int z = blockIdx.z;
  gemm_core(g.A[z], g.Bt[z], g.C[z]);
}

// ---------- output GEMM: 64x128 tile, BK=64 + swizzle (proj structure) ----------
__global__ __launch_bounds__(256) void out_gemm_kernel(
    const unsigned short* __restrict__ A, const unsigned short* __restrict__ Bt,
    float* __restrict__ Cf, const float* __restrict__ bias) {
  constexpr int K = EE, N = EE;
  __shared__ __align__(16) unsigned short As[64 * 64];    // 8KB
  __shared__ __align__(16) unsigned short Bs[128 * 64];   // 16KB
  const int tid = threadIdx.x, lane = tid & 63, w = tid >> 6;
  const int wm = w >> 1, wn = w & 1;
  const int bm = blockIdx.x, bn = blockIdx.y;
  const int g4 = lane >> 4, l15 = lane & 15;

  f32x4 acc[2][4] = {};

  for (int kt = 0; kt < K / 64; ++kt) {
    const int k0 = kt * 64;
#pragma unroll
    for (int it = 0; it < 2; ++it) {                 // A: 512 chunks
      int idx = it * 256 + tid;
      int r = idx >> 3, c = (idx & 7) ^ (r & 7);
      gload_lds16(A + (size_t)(bm * 64 + r) * K + k0 + c * 8, As + idx * 8);
    }
#pragma unroll
    for (int it = 0; it < 4; ++it) {                 // B: 1024 chunks
      int idx = it * 256 + tid;
      int r = idx >> 3, c = (idx & 7) ^ (r & 7);
      gload_lds16(Bt + (size_t)(bn * 128 + r) * K + k0 + c * 8, Bs + idx * 8);
    }
    __syncthreads();
    bf16x8 af[2][2], bf[2][4];
#pragma unroll
    for (int kc2 = 0; kc2 < 2; ++kc2) {
      int co = ((kc2 * 4 + g4) ^ (l15 & 7)) * 8;
#pragma unroll
      for (int i = 0; i < 2; ++i)
        af[kc2][i] = *(const bf16x8*)(As + (wm * 32 + i * 16 + l15) * 64 + co);
#pragma unroll
      for (int j = 0; j < 4; ++j)
        bf[kc2][j] = *(const bf16x8*)(Bs + (wn * 64 + j * 16 + l15) * 64 + co);
    }
#pragma unroll
    for (int kc2 = 0; kc2 < 2; ++kc2)
#pragma unroll
      for (int i = 0; i < 2; ++i)
#pragma unroll
        for (int j = 0; j < 4; ++j)
          acc[i][j] = __builtin_amdgcn_mfma_f32_16x16x32_bf16(
              af[kc2][i], bf[kc2][j], acc[i][j], 0, 0, 0);
    __syncthreads();
  }

  const int rr = g4 * 4;
#pragma unroll
  for (int i = 0; i < 2; ++i)
#pragma unroll
    for (int j = 0; j < 4; ++j) {
      int row = bm * 64 + wm * 32 + i * 16 + rr;
      int col = bn * 128 + wn * 64 + j * 16 + l15;
#pragma unroll
      for (int r = 0; r < 4; ++r)
        Cf[(size_t)(row + r) * N + col] = acc[i][j][r] + bias[col];
    }
}

// ---------- fused attention: in-block split-K, 8 waves, 4 waves/SIMD ----------
// R11 structure; hot-path cross-lane ops (rowmax, rowsum, P-redistribution)
// now via permlane16/32_swap (VALU) instead of shfl_xor (ds_bpermute).
__global__ __launch_bounds__(512, 4) void attn_kernel(
    const unsigned short* __restrict__ q, const unsigned short* __restrict__ k,
    const unsigned short* __restrict__ vt,
    const unsigned long long* __restrict__ mbits,
    unsigned short* __restrict__ av) {
  extern __shared__ __align__(16) char smem[];
  // [0,32K): K, buf*16384 + grp*8192 ; [32K,64K): V, 32768 + buf*16384

  const int tid = threadIdx.x, lane = tid & 63, w = tid >> 6;   // w 0..7
  const int grp = w >> 2, qw = w & 3;
  // ---- XCD-aware bijective remap (512 blocks = 8 XCD x 64) ----
  const int orig = blockIdx.x + 16 * blockIdx.y + 128 * blockIdx.z;
  const int qt = (orig >> 3) & 15;
  const int pair = ((orig & 7) << 2) | (orig >> 7);   // [0,32)
  const int h = pair & 7, b = pair >> 3;
  const int i0 = qt * 64 + qw * 16;
  const int g4 = lane >> 4, l15 = lane & 15;
  const int swz = (l15 & 7) << 4;

  // Q fragments (operand layout: elem row=lane&15, k=(lane>>4)*8+j)
  bf16x8 aq[4];
  {
    const unsigned short* qb =
        q + (size_t)(b * TT + i0 + l15) * EE + h * DD + g4 * 8;
#pragma unroll
    for (int kc = 0; kc < 4; ++kc) aq[kc] = *(const bf16x8*)(qb + kc * 32);
  }

  // ---- staging role (pre-swizzled source chunk, g21 involution) ----
  const unsigned short* sptr[4];
  int ldsb[4];
  size_t sadv;
  if (w < 4) {
    int kg = w >> 1, kh = w & 1;
    const unsigned short* kb0 = k + (size_t)(b * TT) * EE + h * DD;
#pragma unroll
    for (int p = 0; p < 4; ++p) {
      int idx = kh * 256 + p * 64 + lane;
      int kr = idx >> 4, c = (idx & 15) ^ (kr & 7);
      sptr[p] = kb0 + (size_t)(kg * 512 + kr) * EE + c * 8;
      ldsb[p] = kg * 8192 + (kh * 256 + p * 64) * 16;
    }
    sadv = (size_t)32 * EE;
  } else {
    int vw = w - 4;
    const unsigned short* vb0 = vt + (size_t)((b * HH + h) * DD) * TT;
#pragma unroll
    for (int p = 0; p < 4; ++p) {
      int cid = vw * 256 + p * 64 + lane;
      int d = cid >> 3, slot = cid & 7, eff = slot ^ (d & 7);
      sptr[p] = vb0 + (size_t)d * TT + (eff >> 2) * 512 + (eff & 3) * 8;
      ldsb[p] = 32768 + (vw * 256 + p * 64) * 16;
    }
    sadv = 32;
  }

  // mask u32 words: word tau covers kt [32*tau, +32); group offset 16 words
  const unsigned* mb32 =
      (const unsigned*)mbits + ((size_t)(b * TT + i0 + l15) << 5) + grp * 16;
  unsigned mcur = mb32[0];

  int kb_[4];
#pragma unroll
  for (int kc = 0; kc < 4; ++kc)
    kb_[kc] = grp * 8192 + l15 * 256 + ((kc * 64 + g4 * 16) ^ swz);
  const int vb_ = 32768 + l15 * 128 + (((grp * 4 + g4) ^ (l15 & 7)) << 4);

  // prologue: stage tile 0 into buf 0
#pragma unroll
  for (int p = 0; p < 4; ++p) gload_lds16(sptr[p], smem + ldsb[p]);
#pragma unroll
  for (int p = 0; p < 4; ++p) sptr[p] += sadv;

  f32x4 oacc[8] = {};
  float mrun = -__builtin_inff(), lrun = 0.f;   // per lane: q-row = l15

  __syncthreads();
  int bufoff = 0;

  for (int t = 0; t < 16; ++t) {
    // ---- issue next tile into the other buffer (mask word first) ----
    unsigned mnext = 0;
    if (t < 15) {
      mnext = mb32[t + 1];
      int dst = bufoff ^ 16384;
#pragma unroll
      for (int p = 0; p < 4; ++p) gload_lds16(sptr[p], smem + dst + ldsb[p]);
#pragma unroll
      for (int p = 0; p < 4; ++p) sptr[p] += sadv;
    }

    // ---- S^T = K Q^T: lane holds q-row l15, kt32 = nt*16 + g4*4 + r ----
    f32x4 sacc[2] = {};
    __builtin_amdgcn_s_setprio(1);
#pragma unroll
    for (int kc = 0; kc < 4; ++kc)
#pragma unroll
      for (int nt = 0; nt < 2; ++nt) {
        bf16x8 bk = *(const bf16x8*)(smem + bufoff + kb_[kc] + nt * 4096);
        sacc[nt] = __builtin_amdgcn_mfma_f32_16x16x32_bf16(bk, aq[kc],
                                                           sacc[nt], 0, 0, 0);
      }
    __builtin_amdgcn_s_setprio(0);

    // ---- mask: bit==0 -> -1e9 ----
#pragma unroll
    for (int nt = 0; nt < 2; ++nt)
#pragma unroll
      for (int r = 0; r < 4; ++r)
        if (((mcur >> (nt * 16 + g4 * 4 + r)) & 1u) == 0u)
          sacc[nt][r] = -1e9f;

    // ---- row max: lane-local 8 + permlane reduce ----
    float mx = sacc[0][0];
#pragma unroll
    for (int nt = 0; nt < 2; ++nt)
#pragma unroll
      for (int r = 0; r < 4; ++r) mx = fmaxf(mx, sacc[nt][r]);
    mx = qred_max(mx);

    // ---- defer-max (THR=8 in log2 domain) ----
    if (__any(mx > mrun + 8.f)) {
      float mnew = fmaxf(mrun, mx);
      float sc = exp2x(mrun - mnew);   // exp2(-inf)=0 on first tile
      lrun *= sc;
      mrun = mnew;
      float scO[4];
#pragma unroll
      for (int r = 0; r < 4; ++r)
        scO[r] = __shfl(sc, (lane & 48) | (((lane & 48) >> 2) + r), 64);
#pragma unroll
      for (int dt = 0; dt < 8; ++dt)
#pragma unroll
        for (int r = 0; r < 4; ++r) oacc[dt][r] *= scO[r];
    }

    // ---- exp2 + row sum (permlane reduce) ----
    float p2[2][4];
    float s0 = 0.f;
#pragma unroll
    for (int nt = 0; nt < 2; ++nt)
#pragma unroll
      for (int r = 0; r < 4; ++r) {
        float pv = exp2x(sacc[nt][r] - mrun);
        p2[nt][r] = pv;
        s0 += pv;
      }
    lrun += qred_sum(s0);

    // ---- P -> PV A-frag in-register (4 cvt_pk + permlane swaps) ----
    unsigned int paw[4];
    {
      unsigned int D0a = cvtpk(p2[0][0], p2[0][1]);
      unsigned int D1a = cvtpk(p2[0][2], p2[0][3]);
      unsigned int D0b = cvtpk(p2[1][0], p2[1][1]);
      unsigned int D1b = cvtpk(p2[1][2], p2[1][3]);
      unsigned int r1 = lx16(g4 < 2 ? D0a : D0b, lane);
      unsigned int r2 = lx16(g4 < 2 ? D1a : D1b, lane);
      unsigned int r3 = lx32(g4 == 0 ? D0b : D0a, lane);
      unsigned int r4 = lx32(g4 == 0 ? D1b : D1a, lane);
      unsigned int r5 = lx16(lx32(g4 == 2 ? D0a : D0b, lane), lane);
      unsigned int r6 = lx16(lx32(g4 == 2 ? D1a : D1b, lane), lane);
      paw[0] = g4 == 0 ? D0a : g4 == 1 ? r5 : g4 == 2 ? r3 : r1;
      paw[1] = g4 == 0 ? D1a : g4 == 1 ? r6 : g4 == 2 ? r4 : r2;
      paw[2] = g4 == 0 ? r1 : g4 == 1 ? r3 : g4 == 2 ? r5 : D0b;
      paw[3] = g4 == 0 ? r2 : g4 == 1 ? r4 : g4 == 2 ? r6 : D1b;
    }

    // ---- PV: O += P (16x32) @ V (32x128) ----
    __builtin_amdgcn_s_setprio(1);
    {
      union { unsigned int u[4]; bf16x8 v; } pau;
      pau.u[0] = paw[0]; pau.u[1] = paw[1];
      pau.u[2] = paw[2]; pau.u[3] = paw[3];
#pragma unroll
      for (int dt = 0; dt < 8; ++dt) {
        bf16x8 bv = *(const bf16x8*)(smem + bufoff + vb_ + dt * 2048);
        oacc[dt] = __builtin_amdgcn_mfma_f32_16x16x32_bf16(pau.v, bv, oacc[dt],
                                                           0, 0, 0);
      }
    }
    __builtin_amdgcn_s_setprio(0);

    // ---- one barrier: drains prefetch + orders buffer reuse ----
    __syncthreads();
    bufoff ^= 16384;
    mcur = mnext;
  }

  // ---- in-block merge of the two kt-halves ----
  if (grp == 1) {
    char* ob = smem + qw * 8192 + lane * 128;
#pragma unroll
    for (int dt = 0; dt < 8; ++dt)
      *(f32x4*)(ob + ((dt ^ (lane & 7)) * 16)) = oacc[dt];
    float* mlb = (float*)(smem + 32768 + qw * 512 + lane * 8);
    mlb[0] = mrun; mlb[1] = lrun;
  }
  __syncthreads();
  if (grp == 0) {
    const char* ob = smem + qw * 8192 + lane * 128;
    const float* mlb = (const float*)(smem + 32768 + qw * 512 + lane * 8);
    float m2 = mlb[0], l2 = mlb[1];
    float ms = fmaxf(mrun, m2);
    float a1 = exp2x(mrun - ms), a2 = exp2x(m2 - ms);
    float lt = lrun * a1 + l2 * a2;
    float a1O[4], a2O[4], linv[4];
#pragma unroll
    for (int r = 0; r < 4; ++r) {
      int src = (lane & 48) | (((lane & 48) >> 2) + r);
      a1O[r] = __shfl(a1, src, 64);
      a2O[r] = __shfl(a2, src, 64);
      linv[r] = 1.f / __shfl(lt, src, 64);
    }
    unsigned short* obp =
        av + (size_t)(b * TT + i0 + g4 * 4) * EE + h * DD + l15;
#pragma unroll
    for (int dt = 0; dt < 8; ++dt) {
      f32x4 o2 = *(const f32x4*)(ob + ((dt ^ (lane & 7)) * 16));
#pragma unroll
      for (int r = 0; r < 4; ++r)
        obp[(size_t)r * EE + dt * 16] =
            f2b((oacc[dt][r] * a1O[r] + o2[r] * a2O[r]) * linv[r]);
    }
  }
}

// ---------- launch ----------
extern "C" void kernel_launch(void* const* d_in, const int* in_sizes, int n_in,
                              void* d_out, int out_size, void* d_ws,
                              size_t ws_size, hipStream_t stream) {
  const float* query = (const float*)d_in[0];
  const float* key   = (const float*)d_in[1];
  const int*   mask  = (const int*)d_in[2];
  const float* Wq    = (const float*)d_in[3];
  const float* Wk    = (const float*)d_in[4];
  const float* Wv    = (const float*)d_in[5];
  const float* Wu    = (const float*)d_in[6];
  const float* bu    = (const float*)d_in[7];
  float* out = (float*)d_out;

  char* ws = (char*)d_ws;
  const size_t MB = 1024 * 1024;
  unsigned short* qbf = (unsigned short*)(ws);             // 8MB bf16 query
  unsigned short* kbf = (unsigned short*)(ws + 8 * MB);    // 8MB bf16 key
  unsigned short* Wqt = (unsigned short*)(ws + 16 * MB);   // 2MB each, N x K
  unsigned short* Wkt = (unsigned short*)(ws + 18 * MB);
  unsigned short* Wvt = (unsigned short*)(ws + 20 * MB);
  unsigned short* Wut = (unsigned short*)(ws + 22 * MB);
  unsigned short* qp  = (unsigned short*)(ws + 24 * MB);   // q proj
  unsigned short* kp  = (unsigned short*)(ws + 32 * MB);   // k proj
  unsigned short* vp  = (unsigned short*)(ws + 40 * MB);   // v proj
  unsigned short* vtb = (unsigned short*)(ws + 48 * MB);   // v transposed
  unsigned short* av  = (unsigned short*)(ws + 56 * MB);   // attention out
  // mask bits live in the qbf region (dead after proj_gemm; maskpack runs
  // inside the vtrans launch, strictly after proj_gemm).
  unsigned long long* mbt = (unsigned long long*)(ws);     // 512KB

  PrepArgs pa;
  pa.qf = query; pa.kf = key; pa.qb = qbf; pa.kb = kbf;
  pa.wsrc[0] = Wq; pa.wsrc[1] = Wk; pa.wsrc[2] = Wv; pa.wsrc[3] = Wu;
  pa.wdst[0] = Wqt; pa.wdst[1] = Wkt; pa.wdst[2] = Wvt; pa.wdst[3] = Wut;
  pa.wscale[0] = 1.4426950408889634f;   // log2(e): softmax in exp2 domain
  pa.wscale[1] = 1.0f; pa.wscale[2] = 1.0f; pa.wscale[3] = 1.0f;
  prep_kernel<<<8192, 256, 0, stream>>>(pa);

  Gemm3 g3;
  g3.A[0] = qbf; g3.A[1] = kbf; g3.A[2] = kbf;
  g3.Bt[0] = Wqt; g3.Bt[1] = Wkt; g3.Bt[2] = Wvt;
  g3.C[0] = qp; g3.C[1] = kp; g3.C[2] = vp;
  proj_gemm_kernel<<<dim3(32, 8, 3), 256, 0, stream>>>(g3);

  vtrans_mask_kernel<<<5120, 256, 0, stream>>>(vp, vtb, mask, mbt);

  attn_kernel<<<dim3(16, 8, 4), 512, 65536, stream>>>(qp, kp, vtb, mbt, av);

  out_gemm_kernel<<<dim3(64, 8), 256, 0, stream>>>(av, Wut, out, bu);
}